// Round 8
// baseline (1494.727 us; speedup 1.0000x reference)
//
#include <hip/hip_runtime.h>
#include <cstdint>
#include <cstddef>

namespace {

constexpr int NN   = 200000;   // nodes
constexpr int NE   = 800000;   // edges
constexpr int NG   = 4096;     // graphs
constexpr int MAXD = 5;

constexpr int BM = 64;
constexpr int NBC = (NN + 255) / 256;           // 782 preprocessing blocks
constexpr int NBLK  = (NN + BM - 1) / BM + 6;   // 3131 (bucket padding)
constexpr int PERMN = NBLK * BM;                // 200384

typedef _Float16 half8 __attribute__((ext_vector_type(8)));
typedef _Float16 half4 __attribute__((ext_vector_type(4)));
typedef float    f32x4 __attribute__((ext_vector_type(4)));

// packed-weight offsets (fragment-ordered, per layer: 6 * 2*CIN * COUT elems)
constexpr size_t P_L0 = (size_t)6 * 128 * 128;   // 98304
constexpr size_t P_L1 = (size_t)6 * 256 * 128;   // 196608
constexpr size_t P_L2 = (size_t)6 * 256 * 256;   // 393216
constexpr size_t P_L3 = (size_t)6 * 512 * 256;   // 786432
constexpr size_t O_P0 = 0;
constexpr size_t O_P1 = O_P0 + P_L0;
constexpr size_t O_P2 = O_P1 + P_L1;
constexpr size_t O_P3 = O_P2 + P_L2;
constexpr size_t WTOT = O_P3 + P_L3;             // 1,474,560 elements

// ---------------- init / diagnostic ----------------

__global__ void k_memset32(int* __restrict__ p, int v, int n) {
    int i = blockIdx.x * 256 + threadIdx.x;
    if (i < n) p[i] = v;
}

__global__ void k_report(float* __restrict__ outp, float v, int n) {
    int i = blockIdx.x * 256 + threadIdx.x;
    if (i < n) outp[i] = v;
}

// pack fp32 weights into MFMA B-fragment order, f16 hi/lo split.
template <int CIN, int COUT>
__global__ void k_wpack(const float* __restrict__ Wl, const float* __restrict__ Wr,
                        _Float16* __restrict__ hi, _Float16* __restrict__ lo) {
    constexpr int NT = CIN / 16;   // tiles over k = 2*CIN
    constexpr int NB = COUT / 16;
    const int total = 6 * NT * NB * 64;
    int idx = blockIdx.x * 256 + threadIdx.x;
    if (idx >= total) return;
    const int lane = idx & 63;
    int rest = idx >> 6;
    const int nb = rest % NB; rest /= NB;
    const int ti = rest % NT;
    const int d  = rest / NT;
    const int k0 = ti * 32 + ((lane >> 4) * 8);
    const int n  = nb * 16 + (lane & 15);
    half8 hv, lv;
#pragma unroll
    for (int j = 0; j < 8; j++) {
        const int kk = k0 + j;
        const float v = (kk < CIN)
                            ? Wl[((size_t)d * CIN + kk) * COUT + n]
                            : Wr[((size_t)d * CIN + (kk - CIN)) * COUT + n];
        const _Float16 h = (_Float16)v;
        hv[j] = h;
        lv[j] = (_Float16)(v - (float)h);
    }
    *(half8*)(hi + (size_t)idx * 8) = hv;
    *(half8*)(lo + (size_t)idx * 8) = lv;
}

// ---------------- graph preprocessing ----------------

__global__ void k_count_deg(const int* __restrict__ dst, int* __restrict__ deg) {
    int e = blockIdx.x * 256 + threadIdx.x;
    if (e < NE) atomicAdd(&deg[dst[e]], 1);
}

__global__ void k_scan_part(const int* __restrict__ deg, int* __restrict__ part) {
    __shared__ int s[256];
    int t = threadIdx.x, i = blockIdx.x * 256 + t;
    s[t] = (i < NN) ? deg[i] : 0;
    __syncthreads();
    for (int st = 128; st > 0; st >>= 1) {
        if (t < st) s[t] += s[t + st];
        __syncthreads();
    }
    if (t == 0) part[blockIdx.x] = s[0];
}

__global__ void k_scan_single(int* __restrict__ part, int nb) {
    __shared__ int s[1024];
    int t = threadIdx.x;
    int v0 = (t < nb) ? part[t] : 0;
    s[t] = v0;
    __syncthreads();
    for (int off = 1; off < 1024; off <<= 1) {
        int v = (t >= off) ? s[t - off] : 0;
        __syncthreads();
        s[t] += v;
        __syncthreads();
    }
    if (t < nb) part[t] = s[t] - v0;
}

__global__ void k_scan_final(const int* __restrict__ deg, const int* __restrict__ part,
                             int* __restrict__ row_ptr, int* __restrict__ cursor) {
    __shared__ int s[256];
    int t = threadIdx.x, i = blockIdx.x * 256 + t;
    int v0 = (i < NN) ? deg[i] : 0;
    s[t] = v0;
    __syncthreads();
    for (int off = 1; off < 256; off <<= 1) {
        int v = (t >= off) ? s[t - off] : 0;
        __syncthreads();
        s[t] += v;
        __syncthreads();
    }
    if (i < NN) {
        int excl = s[t] - v0 + part[blockIdx.x];
        row_ptr[i] = excl;
        cursor[i]  = excl;
        if (i == NN - 1) row_ptr[NN] = excl + v0;
    }
}

__global__ void k_fill_csr(const int* __restrict__ src, const int* __restrict__ dst,
                           int* __restrict__ cursor, int* __restrict__ col) {
    int e = blockIdx.x * 256 + threadIdx.x;
    if (e < NE) {
        int d = dst[e];
        int slot = atomicAdd(&cursor[d], 1);
        col[slot] = src[e];
    }
}

// -- two-level COARSE bucket counting sort (round-18: revert of the round-17
// -- fine sort, which destroyed block-local node ordering: pool-run
// -- compression fragmented (WRITE 48->66MB) and root/CSR locality worsened
// -- (FETCH 541->573MB) for a net regression).  Coarse sort keeps perm
// -- ~node-ordered within each min(deg,5) bucket. --

__global__ void k_bucket_blockcount(const int* __restrict__ deg, int* __restrict__ blkcnt) {
    __shared__ int h[6];
    int t = threadIdx.x;
    if (t < 6) h[t] = 0;
    __syncthreads();
    int i = blockIdx.x * 256 + t;
    if (i < NN) atomicAdd(&h[min(deg[i], MAXD)], 1);
    __syncthreads();
    if (t < 6) blkcnt[t * NBC + blockIdx.x] = h[t];
}

__global__ void k_bucket_scanall(int* __restrict__ blkcnt, int* __restrict__ bpad) {
    __shared__ int tot[6];
    int t = threadIdx.x;
    if (t < 6) {
        int run = 0;
        for (int j = 0; j < NBC; j++) {
            int v = blkcnt[t * NBC + j];
            blkcnt[t * NBC + j] = run;
            run += v;
        }
        tot[t] = run;
    }
    __syncthreads();
    if (t == 0) {
        int off = 0;
        for (int b = 0; b < 6; b++) {
            bpad[b] = off;
            off += ((tot[b] + BM - 1) / BM) * BM;
        }
        bpad[6] = off;
    }
}

__global__ void k_scatter2(const int* __restrict__ deg, const int* __restrict__ blkcnt,
                           const int* __restrict__ bpad, int* __restrict__ perm) {
    __shared__ int base[6];
    int t = threadIdx.x;
    if (t < 6) base[t] = bpad[t] + blkcnt[t * NBC + blockIdx.x];
    __syncthreads();
    int i = blockIdx.x * 256 + t;
    if (i < NN) {
        int b = min(deg[i], MAXD);
        int pos = atomicAdd(&base[b], 1);
        perm[pos] = i;
    }
}

// ---------------- layer-2a: plain neighbor-sum aggregate ----------------

__global__ void k_aggregate128(const float* __restrict__ hin, const int* __restrict__ row_ptr,
                               const int* __restrict__ col, float* __restrict__ msg) {
    int node = blockIdx.x * 4 + (threadIdx.x >> 6);
    int lane = threadIdx.x & 63;
    int s = row_ptr[node], e = row_ptr[node + 1];
    float2 acc = make_float2(0.f, 0.f);
    int p = s;
    for (; p + 4 <= e; p += 4) {
        const int c0 = col[p], c1 = col[p + 1], c2 = col[p + 2], c3 = col[p + 3];
        const float2 v0 = *(const float2*)(hin + (size_t)c0 * 128 + lane * 2);
        const float2 v1 = *(const float2*)(hin + (size_t)c1 * 128 + lane * 2);
        const float2 v2 = *(const float2*)(hin + (size_t)c2 * 128 + lane * 2);
        const float2 v3 = *(const float2*)(hin + (size_t)c3 * 128 + lane * 2);
        acc.x += (v0.x + v1.x) + (v2.x + v3.x);
        acc.y += (v0.y + v1.y) + (v2.y + v3.y);
    }
    for (; p < e; p++) {
        const float2 v = *(const float2*)(hin + (size_t)col[p] * 128 + lane * 2);
        acc.x += v.x; acc.y += v.y;
    }
    *(float2*)(msg + (size_t)node * 128 + lane * 2) = acc;
}

// ---------------- fused aggregate + transform (round-18) -------------------
//
// Round-17 regression (sort revert above).  Kept: edge-pair unroll (two
// col->row chains in flight; VALUBusy 17.9->16.4).  New: root-row REGISTER
// prefetch - the root loads issue at the end of phase 1 and drain at the
// first barrier (where all waves wait anyway), so phase 1b becomes pure
// convert+store with no load latency in the serial slot.
template <int C0, int C1, int COUT, int MINW, bool POOL_FUSE>
__launch_bounds__(512, MINW)
__global__ void k_transform(const float* __restrict__ hin0, const float* __restrict__ hin1,
                            const int* __restrict__ row_ptr, const int* __restrict__ col,
                            const _Float16* __restrict__ wph, const _Float16* __restrict__ wpl,
                            const float* __restrict__ bias, const float* __restrict__ Wf,
                            const int* __restrict__ perm, const int* __restrict__ deg,
                            const int* __restrict__ batch,
                            float* __restrict__ out0, float* __restrict__ pool,
                            float* __restrict__ logits, int wf_off) {
    constexpr int CIN = C0 + C1;
    constexpr int NW  = CIN / 32;        // k-tiles per operand half (msg/root)
    constexpr int NT  = 2 * NW;          // total k-tiles (weight indexing)
    constexpr int NB  = COUT / 16;
    constexpr int NTN = NB / 8;          // n-tiles per wave (8 waves)
    constexpr int CPT = CIN / 8;         // floats per thread (staging)
    constexpr int UQ  = CPT / 4;         // float4 loads per row per thread
    constexpr int PB_R = POOL_FUSE ? 64 : 1;   // pool staging rows
    constexpr int PB_C = 258;                  // stride == 2 mod 8: 2-way free

    struct FragBuf {
        _Float16 Ah[NW][4][64][8];
        _Float16 Al[NW][4][64][8];
    };
    union SMemU {
        FragBuf f;
        float pbuf[PB_R][PB_C];
    };
    __shared__ SMemU sm;
    __shared__ int rowid[BM];
    __shared__ int gb[BM];
    __shared__ float lsx[8][BM], lsy[8][BM];   // per-wave logits partials

    const int t  = threadIdx.x;
    const int m0 = blockIdx.x * BM;

    if (t < BM) rowid[t] = perm[m0 + t];
    __syncthreads();
    if (rowid[0] < 0) return;  // fully-padded block (uniform exit)

    const int d = min(deg[rowid[0]], MAXD);

    const int am = t & 63, aq = t >> 6;   // lane, wave (0..7)
    const int anode = rowid[am];

    if constexpr (POOL_FUSE) {
        if (t < BM) gb[t] = (rowid[t] >= 0) ? batch[rowid[t]] : -1;
    }

    // ---- phase 1: scattered single-pass gather + 0-conflict staging ----
    // thread (am, aq) owns row am, k-slice [CPT*aq, CPT*aq+CPT).
    const int k0 = CPT * aq;
    const bool lo_half = (C1 == 0) || (k0 < C0);   // slice never straddles
    const float* gsrc = lo_half ? hin0 : hin1;
    const int    gst  = lo_half ? C0 : C1;
    const int    goff = lo_half ? k0 : (k0 - C0);
    const int mt_w = am >> 4, rl = am & 15;
    {
        int es = 0, ee = 0;
        if (anode >= 0) { es = row_ptr[anode]; ee = row_ptr[anode + 1]; }

        f32x4 acc1[UQ];
#pragma unroll
        for (int u = 0; u < UQ; u++) acc1[u] = (f32x4)0.f;
        int p = es;
        // edge-pair unroll: two col->row chains in flight
        for (; p + 2 <= ee; p += 2) {
            const int c0 = col[p], c1 = col[p + 1];
            const float* r0 = gsrc + (size_t)c0 * gst + goff;
            const float* r1 = gsrc + (size_t)c1 * gst + goff;
            f32x4 v0[UQ], v1[UQ];
#pragma unroll
            for (int u = 0; u < UQ; u++) v0[u] = *(const f32x4*)(r0 + 4 * u);
#pragma unroll
            for (int u = 0; u < UQ; u++) v1[u] = *(const f32x4*)(r1 + 4 * u);
#pragma unroll
            for (int u = 0; u < UQ; u++) acc1[u] += v0[u] + v1[u];
        }
        if (p < ee) {
            const float* r = gsrc + (size_t)col[p] * gst + goff;
            f32x4 v[UQ];
#pragma unroll
            for (int u = 0; u < UQ; u++) v[u] = *(const f32x4*)(r + 4 * u);
#pragma unroll
            for (int u = 0; u < UQ; u++) acc1[u] += v[u];
        }
#pragma unroll
        for (int u = 0; u < UQ; u++) {
            const int k  = k0 + 4 * u;
            const int ti = k >> 5;
            const int o  = (k >> 3) & 3;   // k-octet within tile
            const int j0 = k & 7;          // 0 or 4
            half4 hv, lv;
#pragma unroll
            for (int i = 0; i < 4; i++) {
                const _Float16 h = (_Float16)acc1[u][i];
                hv[i] = h; lv[i] = (_Float16)(acc1[u][i] - (float)h);
            }
            *(half4*)&sm.f.Ah[ti][mt_w][rl + 16 * o][j0] = hv;
            *(half4*)&sm.f.Al[ti][mt_w][rl + 16 * o][j0] = lv;
        }
    }

    // root-row register prefetch: issue loads now, they drain at the barrier
    f32x4 rv[UQ];
#pragma unroll
    for (int u = 0; u < UQ; u++) rv[u] = (f32x4)0.f;
    if (anode >= 0) {
        const float* r = gsrc + (size_t)anode * gst + goff;
#pragma unroll
        for (int u = 0; u < UQ; u++) rv[u] = *(const f32x4*)(r + 4 * u);
    }
    __syncthreads();

    const int lx = t & 15, qd = (t >> 4) & 3, wv = t >> 6;
    const int nb0 = wv * NTN;

    f32x4 acc[4][NTN];
#pragma unroll
    for (int mt = 0; mt < 4; mt++)
#pragma unroll
        for (int nt = 0; nt < NTN; nt++) acc[mt][nt] = (f32x4)0.f;

    // ---- phase 2a: msg-tile MFMA sweep (A from LDS) ----
    for (int ti = 0; ti < NW; ti++) {
        half8 bh[NTN], bl[NTN];
        const size_t tbase = (((size_t)d * NT + ti) * NB) * 512;
#pragma unroll
        for (int nt = 0; nt < NTN; nt++) {
            const size_t off = tbase + (size_t)(nb0 + nt) * 512 + (size_t)am * 8;
            bh[nt] = *(const half8*)(wph + off);
            bl[nt] = *(const half8*)(wpl + off);
        }
        half8 ah[4], alo[4];
#pragma unroll
        for (int mt = 0; mt < 4; mt++) {
            ah[mt]  = *(const half8*)&sm.f.Ah[ti][mt][am][0];
            alo[mt] = *(const half8*)&sm.f.Al[ti][mt][am][0];
        }
#pragma unroll
        for (int nt = 0; nt < NTN; nt++)
#pragma unroll
            for (int mt = 0; mt < 4; mt++) {
                acc[mt][nt] = __builtin_amdgcn_mfma_f32_16x16x32_f16(ah[mt],  bh[nt], acc[mt][nt], 0, 0, 0);
                acc[mt][nt] = __builtin_amdgcn_mfma_f32_16x16x32_f16(alo[mt], bh[nt], acc[mt][nt], 0, 0, 0);
                acc[mt][nt] = __builtin_amdgcn_mfma_f32_16x16x32_f16(ah[mt],  bl[nt], acc[mt][nt], 0, 0, 0);
            }
    }
    __syncthreads();   // all msg-fragment reads done before buffer reuse

    // ---- phase 1b: stage prefetched root fragments (pure convert+store) ----
    {
#pragma unroll
        for (int u = 0; u < UQ; u++) {
            const int k  = k0 + 4 * u;
            const int ti = k >> 5;
            const int o  = (k >> 3) & 3;
            const int j0 = k & 7;
            half4 hv, lv;
#pragma unroll
            for (int i = 0; i < 4; i++) {
                const _Float16 h = (_Float16)rv[u][i];
                hv[i] = h; lv[i] = (_Float16)(rv[u][i] - (float)h);
            }
            *(half4*)&sm.f.Ah[ti][mt_w][rl + 16 * o][j0] = hv;
            *(half4*)&sm.f.Al[ti][mt_w][rl + 16 * o][j0] = lv;
        }
    }
    __syncthreads();

    // ---- phase 2b: root-tile MFMA sweep (A from LDS) ----
    for (int ti = 0; ti < NW; ti++) {
        half8 bh[NTN], bl[NTN];
        const size_t tbase = (((size_t)d * NT + NW + ti) * NB) * 512;
#pragma unroll
        for (int nt = 0; nt < NTN; nt++) {
            const size_t off = tbase + (size_t)(nb0 + nt) * 512 + (size_t)am * 8;
            bh[nt] = *(const half8*)(wph + off);
            bl[nt] = *(const half8*)(wpl + off);
        }
        half8 ah[4], alo[4];
#pragma unroll
        for (int mt = 0; mt < 4; mt++) {
            ah[mt]  = *(const half8*)&sm.f.Ah[ti][mt][am][0];
            alo[mt] = *(const half8*)&sm.f.Al[ti][mt][am][0];
        }
#pragma unroll
        for (int nt = 0; nt < NTN; nt++)
#pragma unroll
            for (int mt = 0; mt < 4; mt++) {
                acc[mt][nt] = __builtin_amdgcn_mfma_f32_16x16x32_f16(ah[mt],  bh[nt], acc[mt][nt], 0, 0, 0);
                acc[mt][nt] = __builtin_amdgcn_mfma_f32_16x16x32_f16(alo[mt], bh[nt], acc[mt][nt], 0, 0, 0);
                acc[mt][nt] = __builtin_amdgcn_mfma_f32_16x16x32_f16(ah[mt],  bl[nt], acc[mt][nt], 0, 0, 0);
            }
    }

    // epilogue: lane cols are wv*16*NTN + nt*16 + lx
    float blv[NTN], w0[NTN], w1[NTN];
    int cols[NTN];
#pragma unroll
    for (int nt = 0; nt < NTN; nt++) {
        cols[nt] = wv * (16 * NTN) + nt * 16 + lx;
        blv[nt] = bias[d * COUT + cols[nt]];
        w0[nt]  = Wf[(size_t)(wf_off + cols[nt]) * 2 + 0];
        w1[nt]  = Wf[(size_t)(wf_off + cols[nt]) * 2 + 1];
    }

    // all waves must finish root-fragment reads before pbuf aliasing reuse
    __syncthreads();

#pragma unroll
    for (int mt = 0; mt < 4; mt++)
#pragma unroll
    for (int r = 0; r < 4; r++) {
        const int ri = mt * 16 + qd * 4 + r;
        const int node = rowid[ri];
        float p0 = 0.f, p1 = 0.f;
        float h[NTN];
#pragma unroll
        for (int nt = 0; nt < NTN; nt++) h[nt] = 0.f;
        if (node >= 0) {
#pragma unroll
            for (int nt = 0; nt < NTN; nt++) {
                h[nt] = acc[mt][nt][r] + blv[nt];
                p0 = fmaf(h[nt], w0[nt], p0);
                p1 = fmaf(h[nt], w1[nt], p1);
            }
            if constexpr (!POOL_FUSE) {
                float* orow = out0 + (size_t)node * COUT;
#pragma unroll
                for (int nt = 0; nt < NTN; nt++) orow[cols[nt]] = h[nt];
            }
        }
        if constexpr (POOL_FUSE) {
#pragma unroll
            for (int nt = 0; nt < NTN; nt++) sm.pbuf[ri][cols[nt]] = h[nt];
        }
#pragma unroll
        for (int s = 1; s < 16; s <<= 1) {
            p0 += __shfl_xor(p0, s, 64);
            p1 += __shfl_xor(p1, s, 64);
        }
        if (lx == 0) {          // plain per-wave store (each ri once per wave)
            lsx[wv][ri] = p0;
            lsy[wv][ri] = p1;
        }
    }
    __syncthreads();

    // logits flush: reduce 8 per-wave partials, plain RMW (block owns rows)
    if (t < BM) {
        const int node = rowid[t];
        if (node >= 0) {
            float sx = 0.f, sy = 0.f;
#pragma unroll
            for (int w = 0; w < 8; w++) { sx += lsx[w][t]; sy += lsy[w][t]; }
            logits[(size_t)node * 2 + 0] += sx;
            logits[(size_t)node * 2 + 1] += sy;
        }
    }

    // pool flush: run-compressed by graph id -> ~1 atomic per (run,col)
    if constexpr (POOL_FUSE) {
        const int c  = t & 255;     // col
        const int rh = t >> 8;      // row-half 0/1
        float run = 0.f;
        int rg = -1;
        const int r0 = rh * 32, r1 = r0 + 32;
        for (int r = r0; r < r1; r++) {
            const int g = gb[r];
            if (g != rg) {
                if (rg >= 0) atomicAdd(&pool[(size_t)rg * 256 + c], run);
                run = 0.f; rg = g;
            }
            if (g >= 0) run += sm.pbuf[r][c];
        }
        if (rg >= 0) atomicAdd(&pool[(size_t)rg * 256 + c], run);
    }
}

// ---------------- layer-2b: full-width MFMA GEMM, in-place -----------------

__launch_bounds__(512, 4)
__global__ void k_gemm2b(float* __restrict__ buf0, float* __restrict__ buf1,
                         const _Float16* __restrict__ wph, const _Float16* __restrict__ wpl,
                         const float* __restrict__ bias, const float* __restrict__ Wf,
                         const int* __restrict__ perm, const int* __restrict__ deg,
                         float* __restrict__ logits) {
    constexpr int COUT = 256, NT = 8, NB = 16, NTN = 2;
    __shared__ _Float16 Ah[NT][4][64][8];   // 32 KB
    __shared__ _Float16 Al[NT][4][64][8];   // 32 KB
    __shared__ int rowid[BM];
    __shared__ float lsx[8][BM], lsy[8][BM];

    const int t  = threadIdx.x;
    const int m0 = blockIdx.x * BM;

    if (t < BM) rowid[t] = perm[m0 + t];
    __syncthreads();
    if (rowid[0] < 0) return;

    const int d = min(deg[rowid[0]], MAXD);

    const int am = t & 63, aq = t >> 6;
    const int anode = rowid[am];

    // phase 1: scattered own-row staging (0-conflict stores)
    {
        const int k0 = 32 * aq;
        f32x4 v[8];
#pragma unroll
        for (int u = 0; u < 8; u++) v[u] = (f32x4)0.f;
        if (anode >= 0) {
            const float* r = (aq < 4) ? buf0 + (size_t)anode * 128 + k0
                                      : buf1 + (size_t)anode * 128 + (k0 - 128);
#pragma unroll
            for (int u = 0; u < 8; u++) v[u] = *(const f32x4*)(r + 4 * u);
        }
        const int mt_w = am >> 4, rl = am & 15;
#pragma unroll
        for (int u = 0; u < 8; u++) {
            const int k  = k0 + 4 * u;
            const int ti = k >> 5;
            const int o  = (k >> 3) & 3;
            const int j0 = k & 7;
            half4 hv, lv;
#pragma unroll
            for (int i = 0; i < 4; i++) {
                const _Float16 h = (_Float16)v[u][i];
                hv[i] = h; lv[i] = (_Float16)(v[u][i] - (float)h);
            }
            *(half4*)&Ah[ti][mt_w][rl + 16 * o][j0] = hv;
            *(half4*)&Al[ti][mt_w][rl + 16 * o][j0] = lv;
        }
    }
    __syncthreads();

    const int lx = t & 15, qd = (t >> 4) & 3, wv = t >> 6;
    const int nb0 = wv * NTN;

    f32x4 acc[4][NTN];
#pragma unroll
    for (int mt = 0; mt < 4; mt++)
#pragma unroll
        for (int nt = 0; nt < NTN; nt++) acc[mt][nt] = (f32x4)0.f;

    for (int ti = 0; ti < NT; ti++) {
        half8 bh[NTN], bl[NTN];
        const size_t tbase = (((size_t)d * NT + ti) * NB) * 512;
#pragma unroll
        for (int nt = 0; nt < NTN; nt++) {
            const size_t off = tbase + (size_t)(nb0 + nt) * 512 + (size_t)am * 8;
            bh[nt] = *(const half8*)(wph + off);
            bl[nt] = *(const half8*)(wpl + off);
        }
        half8 ah[4], alo[4];
#pragma unroll
        for (int mt = 0; mt < 4; mt++) {
            ah[mt]  = *(const half8*)&Ah[ti][mt][am][0];
            alo[mt] = *(const half8*)&Al[ti][mt][am][0];
        }
#pragma unroll
        for (int nt = 0; nt < NTN; nt++)
#pragma unroll
            for (int mt = 0; mt < 4; mt++) {
                acc[mt][nt] = __builtin_amdgcn_mfma_f32_16x16x32_f16(ah[mt],  bh[nt], acc[mt][nt], 0, 0, 0);
                acc[mt][nt] = __builtin_amdgcn_mfma_f32_16x16x32_f16(alo[mt], bh[nt], acc[mt][nt], 0, 0, 0);
                acc[mt][nt] = __builtin_amdgcn_mfma_f32_16x16x32_f16(ah[mt],  bl[nt], acc[mt][nt], 0, 0, 0);
            }
    }

    // epilogue: in-place split write + per-wave logits partials (no atomics)
    float blv[NTN], w0[NTN], w1[NTN];
    int cols[NTN];
#pragma unroll
    for (int nt = 0; nt < NTN; nt++) {
        cols[nt] = wv * 32 + nt * 16 + lx;
        blv[nt] = bias[d * COUT + cols[nt]];
        w0[nt]  = Wf[(size_t)(256 + cols[nt]) * 2 + 0];
        w1[nt]  = Wf[(size_t)(256 + cols[nt]) * 2 + 1];
    }
#pragma unroll
    for (int mt = 0; mt < 4; mt++)
#pragma unroll
    for (int r = 0; r < 4; r++) {
        const int ri = mt * 16 + qd * 4 + r;
        const int node = rowid[ri];
        float p0 = 0.f, p1 = 0.f;
        if (node >= 0) {
#pragma unroll
            for (int nt = 0; nt < NTN; nt++) {
                const float h = acc[mt][nt][r] + blv[nt];
                p0 = fmaf(h, w0[nt], p0);
                p1 = fmaf(h, w1[nt], p1);
                if (cols[nt] < 128) buf0[(size_t)node * 128 + cols[nt]] = h;
                else                buf1[(size_t)node * 128 + cols[nt] - 128] = h;
            }
        }
#pragma unroll
        for (int s = 1; s < 16; s <<= 1) {
            p0 += __shfl_xor(p0, s, 64);
            p1 += __shfl_xor(p1, s, 64);
        }
        if (lx == 0) {
            lsx[wv][ri] = p0;
            lsy[wv][ri] = p1;
        }
    }
    __syncthreads();
    if (t < BM) {
        const int node = rowid[t];
        if (node >= 0) {
            float sx = 0.f, sy = 0.f;
#pragma unroll
            for (int w = 0; w < 8; w++) { sx += lsx[w][t]; sy += lsy[w][t]; }
            logits[(size_t)node * 2 + 0] += sx;
            logits[(size_t)node * 2 + 1] += sy;
        }
    }
}

// ---------------- pooling / output ----------------

__global__ void k_pool_logits(const float* __restrict__ pool, const float* __restrict__ Wf,
                              const float* __restrict__ bf, float* __restrict__ pl) {
    int g = blockIdx.x * 4 + (threadIdx.x >> 6);
    int lane = threadIdx.x & 63;
    const float* pr = pool + (size_t)g * 256;
    float p0 = 0.f, p1 = 0.f;
#pragma unroll
    for (int j = 0; j < 4; j++) {
        int k = lane + 64 * j;
        float v = pr[k];
        p0 = fmaf(v, Wf[(size_t)(768 + k) * 2 + 0], p0);
        p1 = fmaf(v, Wf[(size_t)(768 + k) * 2 + 1], p1);
    }
#pragma unroll
    for (int s = 1; s < 64; s <<= 1) {
        p0 += __shfl_xor(p0, s, 64);
        p1 += __shfl_xor(p1, s, 64);
    }
    if (lane == 0) {
        pl[(size_t)g * 2 + 0] = p0 + bf[0];
        pl[(size_t)g * 2 + 1] = p1 + bf[1];
    }
}

__global__ void k_final(const float* __restrict__ logits, const float* __restrict__ pl,
                        const int* __restrict__ batch, float* __restrict__ outp) {
    int i = blockIdx.x * 256 + threadIdx.x;
    if (i < NN) {
        int g = batch[i];
        float l0 = logits[(size_t)i * 2 + 0] + pl[(size_t)g * 2 + 0];
        float l1 = logits[(size_t)i * 2 + 1] + pl[(size_t)g * 2 + 1];
        float m = fmaxf(l0, l1);
        float e0 = expf(l0 - m), e1 = expf(l1 - m);
        float inv = 1.f / (e0 + e1);
        outp[(size_t)i * 2 + 0] = e0 * inv;
        outp[(size_t)i * 2 + 1] = e1 * inv;
    }
}

}  // namespace

extern "C" void kernel_launch(void* const* d_in, const int* in_sizes, int n_in,
                              void* d_out, int out_size, void* d_ws, size_t ws_size,
                              hipStream_t stream) {
    const float* x     = (const float*)d_in[0];
    const int*   ei    = (const int*)d_in[1];
    const int*   batch = (const int*)d_in[2];
    const float* Wl0 = (const float*)d_in[3];  const float* bl0 = (const float*)d_in[4];
    const float* Wr0 = (const float*)d_in[5];
    const float* Wl1 = (const float*)d_in[6];  const float* bl1 = (const float*)d_in[7];
    const float* Wr1 = (const float*)d_in[8];
    const float* Wl2 = (const float*)d_in[9];  const float* bl2 = (const float*)d_in[10];
    const float* Wr2 = (const float*)d_in[11];
    const float* Wl3 = (const float*)d_in[12]; const float* bl3 = (const float*)d_in[13];
    const float* Wr3 = (const float*)d_in[14];
    const float* Wf  = (const float*)d_in[15]; const float* bf  = (const float*)d_in[16];
    const int* src = ei;
    const int* dst = ei + NE;
    float* outp = (float*)d_out;
    (void)in_sizes; (void)n_in;

    // workspace bump allocator (256B aligned).  Total ≈ 224 MB (ws is 256 MB).
    char* w = (char*)d_ws;
    auto alloc = [&](size_t bytes) -> void* {
        void* p = (void*)w;
        w += (bytes + 255) & ~(size_t)255;
        return p;
    };
    // zero-init region (contiguous): deg .. pool
    int*   deg    = (int*)alloc((size_t)NN * 4);
    float* logits = (float*)alloc((size_t)NN * 2 * 4);
    float* pool   = (float*)alloc((size_t)NG * 256 * 4);
    size_t zero_words = (size_t)(w - (char*)deg) / 4;
    // fully-written-by-kernel regions
    int*   bpad    = (int*)alloc(32);
    int*   blkcnt  = (int*)alloc((size_t)6 * NBC * 4);
    int*   perm    = (int*)alloc((size_t)PERMN * 4);      // filled with -1
    int*   row_ptr = (int*)alloc((size_t)(NN + 1) * 4);
    int*   cursor  = (int*)alloc((size_t)NN * 4);
    int*   col     = (int*)alloc((size_t)NE * 4);
    int*   part    = (int*)alloc(1024 * 4);
    float* pl      = (float*)alloc((size_t)NG * 2 * 4);
    _Float16* whi  = (_Float16*)alloc(WTOT * 2);          // packed weights hi
    _Float16* wlo  = (_Float16*)alloc(WTOT * 2);          // packed weights lo
    float* bufA    = (float*)alloc((size_t)NN * 128 * 4); // h0 -> m2 -> h2[:,0:128)
    float* bufB    = (float*)alloc((size_t)NN * 128 * 4); // h1 -> h2[:,128:256)

    size_t required = (size_t)(w - (char*)d_ws);
    if (required > ws_size) {
        k_report<<<(out_size + 255) / 256, 256, 0, stream>>>(
            outp, (float)(double)(ws_size >> 20), out_size);
        return;
    }

    dim3 b256(256);
    dim3 b512(512);
    k_memset32<<<(int)((zero_words + 255) / 256), b256, 0, stream>>>((int*)deg, 0, (int)zero_words);
    k_memset32<<<(PERMN + 255) / 256, b256, 0, stream>>>(perm, -1, PERMN);

    // pack all weights into fragment-ordered f16 hi/lo
    k_wpack<64, 128><<<(int)(P_L0 / 8 + 255) / 256, b256, 0, stream>>>(Wl0, Wr0, whi + O_P0, wlo + O_P0);
    k_wpack<128, 128><<<(int)(P_L1 / 8 + 255) / 256, b256, 0, stream>>>(Wl1, Wr1, whi + O_P1, wlo + O_P1);
    k_wpack<128, 256><<<(int)(P_L2 / 8 + 255) / 256, b256, 0, stream>>>(Wl2, Wr2, whi + O_P2, wlo + O_P2);
    k_wpack<256, 256><<<(int)(P_L3 / 8 + 255) / 256, b256, 0, stream>>>(Wl3, Wr3, whi + O_P3, wlo + O_P3);

    k_count_deg<<<NE / 256, b256, 0, stream>>>(dst, deg);
    k_scan_part<<<NBC, b256, 0, stream>>>(deg, part);
    k_scan_single<<<1, 1024, 0, stream>>>(part, NBC);
    k_scan_final<<<NBC, b256, 0, stream>>>(deg, part, row_ptr, cursor);
    k_fill_csr<<<NE / 256, b256, 0, stream>>>(src, dst, cursor, col);
    k_bucket_blockcount<<<NBC, b256, 0, stream>>>(deg, blkcnt);
    k_bucket_scanall<<<1, 64, 0, stream>>>(blkcnt, bpad);
    k_scatter2<<<NBC, b256, 0, stream>>>(deg, blkcnt, bpad, perm);

    // Layer 0: in=x(64) -> h0=bufA(128)
    k_transform<64, 0, 128, 4, false><<<dim3(NBLK), b512, 0, stream>>>(
        x, nullptr, row_ptr, col, whi + O_P0, wlo + O_P0,
        bl0, Wf, perm, deg, nullptr, bufA, nullptr, logits, 0);
    // Layer 1: in=bufA(128) -> h1=bufB(128)
    k_transform<128, 0, 128, 4, false><<<dim3(NBLK), b512, 0, stream>>>(
        bufA, nullptr, row_ptr, col, whi + O_P1, wlo + O_P1,
        bl1, Wf, perm, deg, nullptr, bufB, nullptr, logits, 128);
    // Layer 2a: m2 = gather-sum(h1) -> bufA
    k_aggregate128<<<NN / 4, b256, 0, stream>>>(bufB, row_ptr, col, bufA);
    // Layer 2b: h2 = [m2|h1] @ [Wl2;Wr2] + bl2, in place -> [bufA|bufB]
    k_gemm2b<<<dim3(NBLK), b512, 0, stream>>>(
        bufA, bufB, whi + O_P2, wlo + O_P2, bl2, Wf, perm, deg, logits);
    // Layer 3: in=[bufA|bufB](256) -> logits chunk + pool (h3 never stored)
    k_transform<128, 128, 256, 4, true><<<dim3(NBLK), b512, 0, stream>>>(
        bufA, bufB, row_ptr, col, whi + O_P3, wlo + O_P3,
        bl3, Wf, perm, deg, batch, nullptr, pool, logits, 512);

    k_pool_logits<<<NG / 4, b256, 0, stream>>>(pool, Wf, bf, pl);
    k_final<<<NBC, b256, 0, stream>>>(logits, pl, batch, outp);
}

// Round 9
// 1214.459 us; speedup vs baseline: 1.2308x; 1.2308x over previous
//
#include <hip/hip_runtime.h>
#include <cstdint>
#include <cstddef>

namespace {

constexpr int NN   = 200000;   // nodes
constexpr int NE   = 800000;   // edges
constexpr int NG   = 4096;     // graphs
constexpr int MAXD = 5;

constexpr int BM = 64;
constexpr int NBC = (NN + 255) / 256;           // 782 preprocessing blocks
constexpr int NBLK  = (NN + BM - 1) / BM + 6;   // 3131 (bucket padding)
constexpr int PERMN = NBLK * BM;                // 200384

typedef _Float16 half8 __attribute__((ext_vector_type(8)));
typedef _Float16 half4 __attribute__((ext_vector_type(4)));
typedef float    f32x4 __attribute__((ext_vector_type(4)));

// packed-weight offsets (fragment-ordered, per layer: 6 * 2*CIN * COUT elems)
constexpr size_t P_L0 = (size_t)6 * 128 * 128;   // 98304
constexpr size_t P_L1 = (size_t)6 * 256 * 128;   // 196608
constexpr size_t P_L2 = (size_t)6 * 256 * 256;   // 393216
constexpr size_t P_L3 = (size_t)6 * 512 * 256;   // 786432
constexpr size_t O_P0 = 0;
constexpr size_t O_P1 = O_P0 + P_L0;
constexpr size_t O_P2 = O_P1 + P_L1;
constexpr size_t O_P3 = O_P2 + P_L2;
constexpr size_t WTOT = O_P3 + P_L3;             // 1,474,560 elements

// ---------------- init / diagnostic ----------------

__global__ void k_memset32(int* __restrict__ p, int v, int n) {
    int i = blockIdx.x * 256 + threadIdx.x;
    if (i < n) p[i] = v;
}

__global__ void k_report(float* __restrict__ outp, float v, int n) {
    int i = blockIdx.x * 256 + threadIdx.x;
    if (i < n) outp[i] = v;
}

// pack fp32 weights into MFMA B-fragment order, f16 hi/lo split.
template <int CIN, int COUT>
__global__ void k_wpack(const float* __restrict__ Wl, const float* __restrict__ Wr,
                        _Float16* __restrict__ hi, _Float16* __restrict__ lo) {
    constexpr int NT = CIN / 16;   // tiles over k = 2*CIN
    constexpr int NB = COUT / 16;
    const int total = 6 * NT * NB * 64;
    int idx = blockIdx.x * 256 + threadIdx.x;
    if (idx >= total) return;
    const int lane = idx & 63;
    int rest = idx >> 6;
    const int nb = rest % NB; rest /= NB;
    const int ti = rest % NT;
    const int d  = rest / NT;
    const int k0 = ti * 32 + ((lane >> 4) * 8);
    const int n  = nb * 16 + (lane & 15);
    half8 hv, lv;
#pragma unroll
    for (int j = 0; j < 8; j++) {
        const int kk = k0 + j;
        const float v = (kk < CIN)
                            ? Wl[((size_t)d * CIN + kk) * COUT + n]
                            : Wr[((size_t)d * CIN + (kk - CIN)) * COUT + n];
        const _Float16 h = (_Float16)v;
        hv[j] = h;
        lv[j] = (_Float16)(v - (float)h);
    }
    *(half8*)(hi + (size_t)idx * 8) = hv;
    *(half8*)(lo + (size_t)idx * 8) = lv;
}

// ---------------- graph preprocessing ----------------

__global__ void k_count_deg(const int* __restrict__ dst, int* __restrict__ deg) {
    int e = blockIdx.x * 256 + threadIdx.x;
    if (e < NE) atomicAdd(&deg[dst[e]], 1);
}

__global__ void k_scan_part(const int* __restrict__ deg, int* __restrict__ part) {
    __shared__ int s[256];
    int t = threadIdx.x, i = blockIdx.x * 256 + t;
    s[t] = (i < NN) ? deg[i] : 0;
    __syncthreads();
    for (int st = 128; st > 0; st >>= 1) {
        if (t < st) s[t] += s[t + st];
        __syncthreads();
    }
    if (t == 0) part[blockIdx.x] = s[0];
}

__global__ void k_scan_single(int* __restrict__ part, int nb) {
    __shared__ int s[1024];
    int t = threadIdx.x;
    int v0 = (t < nb) ? part[t] : 0;
    s[t] = v0;
    __syncthreads();
    for (int off = 1; off < 1024; off <<= 1) {
        int v = (t >= off) ? s[t - off] : 0;
        __syncthreads();
        s[t] += v;
        __syncthreads();
    }
    if (t < nb) part[t] = s[t] - v0;
}

__global__ void k_scan_final(const int* __restrict__ deg, const int* __restrict__ part,
                             int* __restrict__ row_ptr, int* __restrict__ cursor) {
    __shared__ int s[256];
    int t = threadIdx.x, i = blockIdx.x * 256 + t;
    int v0 = (i < NN) ? deg[i] : 0;
    s[t] = v0;
    __syncthreads();
    for (int off = 1; off < 256; off <<= 1) {
        int v = (t >= off) ? s[t - off] : 0;
        __syncthreads();
        s[t] += v;
        __syncthreads();
    }
    if (i < NN) {
        int excl = s[t] - v0 + part[blockIdx.x];
        row_ptr[i] = excl;
        cursor[i]  = excl;
        if (i == NN - 1) row_ptr[NN] = excl + v0;
    }
}

__global__ void k_fill_csr(const int* __restrict__ src, const int* __restrict__ dst,
                           int* __restrict__ cursor, int* __restrict__ col) {
    int e = blockIdx.x * 256 + threadIdx.x;
    if (e < NE) {
        int d = dst[e];
        int slot = atomicAdd(&cursor[d], 1);
        col[slot] = src[e];
    }
}

// -- two-level COARSE bucket counting sort (keeps perm ~node-ordered within
// -- each min(deg,5) bucket; fine sort destroyed locality - round-17) --

__global__ void k_bucket_blockcount(const int* __restrict__ deg, int* __restrict__ blkcnt) {
    __shared__ int h[6];
    int t = threadIdx.x;
    if (t < 6) h[t] = 0;
    __syncthreads();
    int i = blockIdx.x * 256 + t;
    if (i < NN) atomicAdd(&h[min(deg[i], MAXD)], 1);
    __syncthreads();
    if (t < 6) blkcnt[t * NBC + blockIdx.x] = h[t];
}

__global__ void k_bucket_scanall(int* __restrict__ blkcnt, int* __restrict__ bpad) {
    __shared__ int tot[6];
    int t = threadIdx.x;
    if (t < 6) {
        int run = 0;
        for (int j = 0; j < NBC; j++) {
            int v = blkcnt[t * NBC + j];
            blkcnt[t * NBC + j] = run;
            run += v;
        }
        tot[t] = run;
    }
    __syncthreads();
    if (t == 0) {
        int off = 0;
        for (int b = 0; b < 6; b++) {
            bpad[b] = off;
            off += ((tot[b] + BM - 1) / BM) * BM;
        }
        bpad[6] = off;
    }
}

__global__ void k_scatter2(const int* __restrict__ deg, const int* __restrict__ blkcnt,
                           const int* __restrict__ bpad, int* __restrict__ perm) {
    __shared__ int base[6];
    int t = threadIdx.x;
    if (t < 6) base[t] = bpad[t] + blkcnt[t * NBC + blockIdx.x];
    __syncthreads();
    int i = blockIdx.x * 256 + t;
    if (i < NN) {
        int b = min(deg[i], MAXD);
        int pos = atomicAdd(&base[b], 1);
        perm[pos] = i;
    }
}

// ---------------- layer-2a: plain neighbor-sum aggregate ----------------

__global__ void k_aggregate128(const float* __restrict__ hin, const int* __restrict__ row_ptr,
                               const int* __restrict__ col, float* __restrict__ msg) {
    int node = blockIdx.x * 4 + (threadIdx.x >> 6);
    int lane = threadIdx.x & 63;
    int s = row_ptr[node], e = row_ptr[node + 1];
    float2 acc = make_float2(0.f, 0.f);
    int p = s;
    for (; p + 4 <= e; p += 4) {
        const int c0 = col[p], c1 = col[p + 1], c2 = col[p + 2], c3 = col[p + 3];
        const float2 v0 = *(const float2*)(hin + (size_t)c0 * 128 + lane * 2);
        const float2 v1 = *(const float2*)(hin + (size_t)c1 * 128 + lane * 2);
        const float2 v2 = *(const float2*)(hin + (size_t)c2 * 128 + lane * 2);
        const float2 v3 = *(const float2*)(hin + (size_t)c3 * 128 + lane * 2);
        acc.x += (v0.x + v1.x) + (v2.x + v3.x);
        acc.y += (v0.y + v1.y) + (v2.y + v3.y);
    }
    for (; p < e; p++) {
        const float2 v = *(const float2*)(hin + (size_t)col[p] * 128 + lane * 2);
        acc.x += v.x; acc.y += v.y;
    }
    *(float2*)(msg + (size_t)node * 128 + lane * 2) = acc;
}

// ---------------- fused aggregate + transform (round-19) -------------------
//
// Round-18 post-mortem: the root-row REGISTER prefetch (rv[8] live across
// phase-2a's register-pressure peak) spilled to scratch: WRITE 48->743MB,
// FETCH 541->958MB, layer-3 423->725us.  Lesson (rule-#20 cousin): a
// "free" prefetch living across a high-pressure region isn't free.
// Round-19 = round-16 structure EXACTLY (measured 1207us total, 423us L3,
// 48MB WRITE) + ONE isolated addition: edge-pair unroll in the phase-1
// gather (register cost scoped inside phase 1, dies before phase 2a).
template <int C0, int C1, int COUT, int MINW, bool POOL_FUSE>
__launch_bounds__(512, MINW)
__global__ void k_transform(const float* __restrict__ hin0, const float* __restrict__ hin1,
                            const int* __restrict__ row_ptr, const int* __restrict__ col,
                            const _Float16* __restrict__ wph, const _Float16* __restrict__ wpl,
                            const float* __restrict__ bias, const float* __restrict__ Wf,
                            const int* __restrict__ perm, const int* __restrict__ deg,
                            const int* __restrict__ batch,
                            float* __restrict__ out0, float* __restrict__ pool,
                            float* __restrict__ logits, int wf_off) {
    constexpr int CIN = C0 + C1;
    constexpr int NW  = CIN / 32;        // k-tiles per operand half (msg/root)
    constexpr int NT  = 2 * NW;          // total k-tiles (weight indexing)
    constexpr int NB  = COUT / 16;
    constexpr int NTN = NB / 8;          // n-tiles per wave (8 waves)
    constexpr int CPT = CIN / 8;         // floats per thread (staging)
    constexpr int UQ  = CPT / 4;         // float4 loads per row per thread
    constexpr int PB_R = POOL_FUSE ? 64 : 1;   // pool staging rows
    constexpr int PB_C = 258;                  // stride == 2 mod 8: 2-way free

    struct FragBuf {
        _Float16 Ah[NW][4][64][8];
        _Float16 Al[NW][4][64][8];
    };
    union SMemU {
        FragBuf f;
        float pbuf[PB_R][PB_C];
    };
    __shared__ SMemU sm;
    __shared__ int rowid[BM];
    __shared__ int gb[BM];
    __shared__ float lsx[8][BM], lsy[8][BM];   // per-wave logits partials

    const int t  = threadIdx.x;
    const int m0 = blockIdx.x * BM;

    if (t < BM) rowid[t] = perm[m0 + t];
    __syncthreads();
    if (rowid[0] < 0) return;  // fully-padded block (uniform exit)

    const int d = min(deg[rowid[0]], MAXD);

    const int am = t & 63, aq = t >> 6;   // lane, wave (0..7)
    const int anode = rowid[am];

    if constexpr (POOL_FUSE) {
        if (t < BM) gb[t] = (rowid[t] >= 0) ? batch[rowid[t]] : -1;
    }

    // ---- phase 1: scattered single-pass gather + 0-conflict staging ----
    // thread (am, aq) owns row am, k-slice [CPT*aq, CPT*aq+CPT).
    const int k0 = CPT * aq;
    const bool lo_half = (C1 == 0) || (k0 < C0);   // slice never straddles
    const float* gsrc = lo_half ? hin0 : hin1;
    const int    gst  = lo_half ? C0 : C1;
    const int    goff = lo_half ? k0 : (k0 - C0);
    const int mt_w = am >> 4, rl = am & 15;
    {
        int es = 0, ee = 0;
        if (anode >= 0) { es = row_ptr[anode]; ee = row_ptr[anode + 1]; }

        f32x4 acc1[UQ];
#pragma unroll
        for (int u = 0; u < UQ; u++) acc1[u] = (f32x4)0.f;
        int p = es;
        // edge-pair unroll: two col->row chains in flight (regs die here)
        for (; p + 2 <= ee; p += 2) {
            const int c0 = col[p], c1 = col[p + 1];
            const float* r0 = gsrc + (size_t)c0 * gst + goff;
            const float* r1 = gsrc + (size_t)c1 * gst + goff;
            f32x4 v0[UQ], v1[UQ];
#pragma unroll
            for (int u = 0; u < UQ; u++) v0[u] = *(const f32x4*)(r0 + 4 * u);
#pragma unroll
            for (int u = 0; u < UQ; u++) v1[u] = *(const f32x4*)(r1 + 4 * u);
#pragma unroll
            for (int u = 0; u < UQ; u++) acc1[u] += v0[u] + v1[u];
        }
        if (p < ee) {
            const float* r = gsrc + (size_t)col[p] * gst + goff;
            f32x4 v[UQ];
#pragma unroll
            for (int u = 0; u < UQ; u++) v[u] = *(const f32x4*)(r + 4 * u);
#pragma unroll
            for (int u = 0; u < UQ; u++) acc1[u] += v[u];
        }
#pragma unroll
        for (int u = 0; u < UQ; u++) {
            const int k  = k0 + 4 * u;
            const int ti = k >> 5;
            const int o  = (k >> 3) & 3;   // k-octet within tile
            const int j0 = k & 7;          // 0 or 4
            half4 hv, lv;
#pragma unroll
            for (int i = 0; i < 4; i++) {
                const _Float16 h = (_Float16)acc1[u][i];
                hv[i] = h; lv[i] = (_Float16)(acc1[u][i] - (float)h);
            }
            *(half4*)&sm.f.Ah[ti][mt_w][rl + 16 * o][j0] = hv;
            *(half4*)&sm.f.Al[ti][mt_w][rl + 16 * o][j0] = lv;
        }
    }
    __syncthreads();

    const int lx = t & 15, qd = (t >> 4) & 3, wv = t >> 6;
    const int nb0 = wv * NTN;

    f32x4 acc[4][NTN];
#pragma unroll
    for (int mt = 0; mt < 4; mt++)
#pragma unroll
        for (int nt = 0; nt < NTN; nt++) acc[mt][nt] = (f32x4)0.f;

    // ---- phase 2a: msg-tile MFMA sweep (A from LDS) ----
    for (int ti = 0; ti < NW; ti++) {
        half8 bh[NTN], bl[NTN];
        const size_t tbase = (((size_t)d * NT + ti) * NB) * 512;
#pragma unroll
        for (int nt = 0; nt < NTN; nt++) {
            const size_t off = tbase + (size_t)(nb0 + nt) * 512 + (size_t)am * 8;
            bh[nt] = *(const half8*)(wph + off);
            bl[nt] = *(const half8*)(wpl + off);
        }
        half8 ah[4], alo[4];
#pragma unroll
        for (int mt = 0; mt < 4; mt++) {
            ah[mt]  = *(const half8*)&sm.f.Ah[ti][mt][am][0];
            alo[mt] = *(const half8*)&sm.f.Al[ti][mt][am][0];
        }
#pragma unroll
        for (int nt = 0; nt < NTN; nt++)
#pragma unroll
            for (int mt = 0; mt < 4; mt++) {
                acc[mt][nt] = __builtin_amdgcn_mfma_f32_16x16x32_f16(ah[mt],  bh[nt], acc[mt][nt], 0, 0, 0);
                acc[mt][nt] = __builtin_amdgcn_mfma_f32_16x16x32_f16(alo[mt], bh[nt], acc[mt][nt], 0, 0, 0);
                acc[mt][nt] = __builtin_amdgcn_mfma_f32_16x16x32_f16(ah[mt],  bl[nt], acc[mt][nt], 0, 0, 0);
            }
    }
    __syncthreads();   // all msg-fragment reads done before buffer reuse

    // ---- phase 1b: stage root fragments into the same LDS (read once) ----
    {
        f32x4 v[UQ];
#pragma unroll
        for (int u = 0; u < UQ; u++) v[u] = (f32x4)0.f;
        if (anode >= 0) {
            const float* r = gsrc + (size_t)anode * gst + goff;
#pragma unroll
            for (int u = 0; u < UQ; u++) v[u] = *(const f32x4*)(r + 4 * u);
        }
#pragma unroll
        for (int u = 0; u < UQ; u++) {
            const int k  = k0 + 4 * u;
            const int ti = k >> 5;
            const int o  = (k >> 3) & 3;
            const int j0 = k & 7;
            half4 hv, lv;
#pragma unroll
            for (int i = 0; i < 4; i++) {
                const _Float16 h = (_Float16)v[u][i];
                hv[i] = h; lv[i] = (_Float16)(v[u][i] - (float)h);
            }
            *(half4*)&sm.f.Ah[ti][mt_w][rl + 16 * o][j0] = hv;
            *(half4*)&sm.f.Al[ti][mt_w][rl + 16 * o][j0] = lv;
        }
    }
    __syncthreads();

    // ---- phase 2b: root-tile MFMA sweep (A from LDS) ----
    for (int ti = 0; ti < NW; ti++) {
        half8 bh[NTN], bl[NTN];
        const size_t tbase = (((size_t)d * NT + NW + ti) * NB) * 512;
#pragma unroll
        for (int nt = 0; nt < NTN; nt++) {
            const size_t off = tbase + (size_t)(nb0 + nt) * 512 + (size_t)am * 8;
            bh[nt] = *(const half8*)(wph + off);
            bl[nt] = *(const half8*)(wpl + off);
        }
        half8 ah[4], alo[4];
#pragma unroll
        for (int mt = 0; mt < 4; mt++) {
            ah[mt]  = *(const half8*)&sm.f.Ah[ti][mt][am][0];
            alo[mt] = *(const half8*)&sm.f.Al[ti][mt][am][0];
        }
#pragma unroll
        for (int nt = 0; nt < NTN; nt++)
#pragma unroll
            for (int mt = 0; mt < 4; mt++) {
                acc[mt][nt] = __builtin_amdgcn_mfma_f32_16x16x32_f16(ah[mt],  bh[nt], acc[mt][nt], 0, 0, 0);
                acc[mt][nt] = __builtin_amdgcn_mfma_f32_16x16x32_f16(alo[mt], bh[nt], acc[mt][nt], 0, 0, 0);
                acc[mt][nt] = __builtin_amdgcn_mfma_f32_16x16x32_f16(ah[mt],  bl[nt], acc[mt][nt], 0, 0, 0);
            }
    }

    // epilogue: lane cols are wv*16*NTN + nt*16 + lx
    float blv[NTN], w0[NTN], w1[NTN];
    int cols[NTN];
#pragma unroll
    for (int nt = 0; nt < NTN; nt++) {
        cols[nt] = wv * (16 * NTN) + nt * 16 + lx;
        blv[nt] = bias[d * COUT + cols[nt]];
        w0[nt]  = Wf[(size_t)(wf_off + cols[nt]) * 2 + 0];
        w1[nt]  = Wf[(size_t)(wf_off + cols[nt]) * 2 + 1];
    }

    // all waves must finish root-fragment reads before pbuf aliasing reuse
    __syncthreads();

#pragma unroll
    for (int mt = 0; mt < 4; mt++)
#pragma unroll
    for (int r = 0; r < 4; r++) {
        const int ri = mt * 16 + qd * 4 + r;
        const int node = rowid[ri];
        float p0 = 0.f, p1 = 0.f;
        float h[NTN];
#pragma unroll
        for (int nt = 0; nt < NTN; nt++) h[nt] = 0.f;
        if (node >= 0) {
#pragma unroll
            for (int nt = 0; nt < NTN; nt++) {
                h[nt] = acc[mt][nt][r] + blv[nt];
                p0 = fmaf(h[nt], w0[nt], p0);
                p1 = fmaf(h[nt], w1[nt], p1);
            }
            if constexpr (!POOL_FUSE) {
                float* orow = out0 + (size_t)node * COUT;
#pragma unroll
                for (int nt = 0; nt < NTN; nt++) orow[cols[nt]] = h[nt];
            }
        }
        if constexpr (POOL_FUSE) {
#pragma unroll
            for (int nt = 0; nt < NTN; nt++) sm.pbuf[ri][cols[nt]] = h[nt];
        }
#pragma unroll
        for (int s = 1; s < 16; s <<= 1) {
            p0 += __shfl_xor(p0, s, 64);
            p1 += __shfl_xor(p1, s, 64);
        }
        if (lx == 0) {          // plain per-wave store (each ri once per wave)
            lsx[wv][ri] = p0;
            lsy[wv][ri] = p1;
        }
    }
    __syncthreads();

    // logits flush: reduce 8 per-wave partials, plain RMW (block owns rows)
    if (t < BM) {
        const int node = rowid[t];
        if (node >= 0) {
            float sx = 0.f, sy = 0.f;
#pragma unroll
            for (int w = 0; w < 8; w++) { sx += lsx[w][t]; sy += lsy[w][t]; }
            logits[(size_t)node * 2 + 0] += sx;
            logits[(size_t)node * 2 + 1] += sy;
        }
    }

    // pool flush: run-compressed by graph id -> ~1 atomic per (run,col)
    if constexpr (POOL_FUSE) {
        const int c  = t & 255;     // col
        const int rh = t >> 8;      // row-half 0/1
        float run = 0.f;
        int rg = -1;
        const int r0 = rh * 32, r1 = r0 + 32;
        for (int r = r0; r < r1; r++) {
            const int g = gb[r];
            if (g != rg) {
                if (rg >= 0) atomicAdd(&pool[(size_t)rg * 256 + c], run);
                run = 0.f; rg = g;
            }
            if (g >= 0) run += sm.pbuf[r][c];
        }
        if (rg >= 0) atomicAdd(&pool[(size_t)rg * 256 + c], run);
    }
}

// ---------------- layer-2b: full-width MFMA GEMM, in-place -----------------

__launch_bounds__(512, 4)
__global__ void k_gemm2b(float* __restrict__ buf0, float* __restrict__ buf1,
                         const _Float16* __restrict__ wph, const _Float16* __restrict__ wpl,
                         const float* __restrict__ bias, const float* __restrict__ Wf,
                         const int* __restrict__ perm, const int* __restrict__ deg,
                         float* __restrict__ logits) {
    constexpr int COUT = 256, NT = 8, NB = 16, NTN = 2;
    __shared__ _Float16 Ah[NT][4][64][8];   // 32 KB
    __shared__ _Float16 Al[NT][4][64][8];   // 32 KB
    __shared__ int rowid[BM];
    __shared__ float lsx[8][BM], lsy[8][BM];

    const int t  = threadIdx.x;
    const int m0 = blockIdx.x * BM;

    if (t < BM) rowid[t] = perm[m0 + t];
    __syncthreads();
    if (rowid[0] < 0) return;

    const int d = min(deg[rowid[0]], MAXD);

    const int am = t & 63, aq = t >> 6;
    const int anode = rowid[am];

    // phase 1: scattered own-row staging (0-conflict stores)
    {
        const int k0 = 32 * aq;
        f32x4 v[8];
#pragma unroll
        for (int u = 0; u < 8; u++) v[u] = (f32x4)0.f;
        if (anode >= 0) {
            const float* r = (aq < 4) ? buf0 + (size_t)anode * 128 + k0
                                      : buf1 + (size_t)anode * 128 + (k0 - 128);
#pragma unroll
            for (int u = 0; u < 8; u++) v[u] = *(const f32x4*)(r + 4 * u);
        }
        const int mt_w = am >> 4, rl = am & 15;
#pragma unroll
        for (int u = 0; u < 8; u++) {
            const int k  = k0 + 4 * u;
            const int ti = k >> 5;
            const int o  = (k >> 3) & 3;
            const int j0 = k & 7;
            half4 hv, lv;
#pragma unroll
            for (int i = 0; i < 4; i++) {
                const _Float16 h = (_Float16)v[u][i];
                hv[i] = h; lv[i] = (_Float16)(v[u][i] - (float)h);
            }
            *(half4*)&Ah[ti][mt_w][rl + 16 * o][j0] = hv;
            *(half4*)&Al[ti][mt_w][rl + 16 * o][j0] = lv;
        }
    }
    __syncthreads();

    const int lx = t & 15, qd = (t >> 4) & 3, wv = t >> 6;
    const int nb0 = wv * NTN;

    f32x4 acc[4][NTN];
#pragma unroll
    for (int mt = 0; mt < 4; mt++)
#pragma unroll
        for (int nt = 0; nt < NTN; nt++) acc[mt][nt] = (f32x4)0.f;

    for (int ti = 0; ti < NT; ti++) {
        half8 bh[NTN], bl[NTN];
        const size_t tbase = (((size_t)d * NT + ti) * NB) * 512;
#pragma unroll
        for (int nt = 0; nt < NTN; nt++) {
            const size_t off = tbase + (size_t)(nb0 + nt) * 512 + (size_t)am * 8;
            bh[nt] = *(const half8*)(wph + off);
            bl[nt] = *(const half8*)(wpl + off);
        }
        half8 ah[4], alo[4];
#pragma unroll
        for (int mt = 0; mt < 4; mt++) {
            ah[mt]  = *(const half8*)&Ah[ti][mt][am][0];
            alo[mt] = *(const half8*)&Al[ti][mt][am][0];
        }
#pragma unroll
        for (int nt = 0; nt < NTN; nt++)
#pragma unroll
            for (int mt = 0; mt < 4; mt++) {
                acc[mt][nt] = __builtin_amdgcn_mfma_f32_16x16x32_f16(ah[mt],  bh[nt], acc[mt][nt], 0, 0, 0);
                acc[mt][nt] = __builtin_amdgcn_mfma_f32_16x16x32_f16(alo[mt], bh[nt], acc[mt][nt], 0, 0, 0);
                acc[mt][nt] = __builtin_amdgcn_mfma_f32_16x16x32_f16(ah[mt],  bl[nt], acc[mt][nt], 0, 0, 0);
            }
    }

    // epilogue: in-place split write + per-wave logits partials (no atomics)
    float blv[NTN], w0[NTN], w1[NTN];
    int cols[NTN];
#pragma unroll
    for (int nt = 0; nt < NTN; nt++) {
        cols[nt] = wv * 32 + nt * 16 + lx;
        blv[nt] = bias[d * COUT + cols[nt]];
        w0[nt]  = Wf[(size_t)(256 + cols[nt]) * 2 + 0];
        w1[nt]  = Wf[(size_t)(256 + cols[nt]) * 2 + 1];
    }
#pragma unroll
    for (int mt = 0; mt < 4; mt++)
#pragma unroll
    for (int r = 0; r < 4; r++) {
        const int ri = mt * 16 + qd * 4 + r;
        const int node = rowid[ri];
        float p0 = 0.f, p1 = 0.f;
        if (node >= 0) {
#pragma unroll
            for (int nt = 0; nt < NTN; nt++) {
                const float h = acc[mt][nt][r] + blv[nt];
                p0 = fmaf(h, w0[nt], p0);
                p1 = fmaf(h, w1[nt], p1);
                if (cols[nt] < 128) buf0[(size_t)node * 128 + cols[nt]] = h;
                else                buf1[(size_t)node * 128 + cols[nt] - 128] = h;
            }
        }
#pragma unroll
        for (int s = 1; s < 16; s <<= 1) {
            p0 += __shfl_xor(p0, s, 64);
            p1 += __shfl_xor(p1, s, 64);
        }
        if (lx == 0) {
            lsx[wv][ri] = p0;
            lsy[wv][ri] = p1;
        }
    }
    __syncthreads();
    if (t < BM) {
        const int node = rowid[t];
        if (node >= 0) {
            float sx = 0.f, sy = 0.f;
#pragma unroll
            for (int w = 0; w < 8; w++) { sx += lsx[w][t]; sy += lsy[w][t]; }
            logits[(size_t)node * 2 + 0] += sx;
            logits[(size_t)node * 2 + 1] += sy;
        }
    }
}

// ---------------- pooling / output ----------------

__global__ void k_pool_logits(const float* __restrict__ pool, const float* __restrict__ Wf,
                              const float* __restrict__ bf, float* __restrict__ pl) {
    int g = blockIdx.x * 4 + (threadIdx.x >> 6);
    int lane = threadIdx.x & 63;
    const float* pr = pool + (size_t)g * 256;
    float p0 = 0.f, p1 = 0.f;
#pragma unroll
    for (int j = 0; j < 4; j++) {
        int k = lane + 64 * j;
        float v = pr[k];
        p0 = fmaf(v, Wf[(size_t)(768 + k) * 2 + 0], p0);
        p1 = fmaf(v, Wf[(size_t)(768 + k) * 2 + 1], p1);
    }
#pragma unroll
    for (int s = 1; s < 64; s <<= 1) {
        p0 += __shfl_xor(p0, s, 64);
        p1 += __shfl_xor(p1, s, 64);
    }
    if (lane == 0) {
        pl[(size_t)g * 2 + 0] = p0 + bf[0];
        pl[(size_t)g * 2 + 1] = p1 + bf[1];
    }
}

__global__ void k_final(const float* __restrict__ logits, const float* __restrict__ pl,
                        const int* __restrict__ batch, float* __restrict__ outp) {
    int i = blockIdx.x * 256 + threadIdx.x;
    if (i < NN) {
        int g = batch[i];
        float l0 = logits[(size_t)i * 2 + 0] + pl[(size_t)g * 2 + 0];
        float l1 = logits[(size_t)i * 2 + 1] + pl[(size_t)g * 2 + 1];
        float m = fmaxf(l0, l1);
        float e0 = expf(l0 - m), e1 = expf(l1 - m);
        float inv = 1.f / (e0 + e1);
        outp[(size_t)i * 2 + 0] = e0 * inv;
        outp[(size_t)i * 2 + 1] = e1 * inv;
    }
}

}  // namespace

extern "C" void kernel_launch(void* const* d_in, const int* in_sizes, int n_in,
                              void* d_out, int out_size, void* d_ws, size_t ws_size,
                              hipStream_t stream) {
    const float* x     = (const float*)d_in[0];
    const int*   ei    = (const int*)d_in[1];
    const int*   batch = (const int*)d_in[2];
    const float* Wl0 = (const float*)d_in[3];  const float* bl0 = (const float*)d_in[4];
    const float* Wr0 = (const float*)d_in[5];
    const float* Wl1 = (const float*)d_in[6];  const float* bl1 = (const float*)d_in[7];
    const float* Wr1 = (const float*)d_in[8];
    const float* Wl2 = (const float*)d_in[9];  const float* bl2 = (const float*)d_in[10];
    const float* Wr2 = (const float*)d_in[11];
    const float* Wl3 = (const float*)d_in[12]; const float* bl3 = (const float*)d_in[13];
    const float* Wr3 = (const float*)d_in[14];
    const float* Wf  = (const float*)d_in[15]; const float* bf  = (const float*)d_in[16];
    const int* src = ei;
    const int* dst = ei + NE;
    float* outp = (float*)d_out;
    (void)in_sizes; (void)n_in;

    // workspace bump allocator (256B aligned).  Total ≈ 224 MB (ws is 256 MB).
    char* w = (char*)d_ws;
    auto alloc = [&](size_t bytes) -> void* {
        void* p = (void*)w;
        w += (bytes + 255) & ~(size_t)255;
        return p;
    };
    // zero-init region (contiguous): deg .. pool
    int*   deg    = (int*)alloc((size_t)NN * 4);
    float* logits = (float*)alloc((size_t)NN * 2 * 4);
    float* pool   = (float*)alloc((size_t)NG * 256 * 4);
    size_t zero_words = (size_t)(w - (char*)deg) / 4;
    // fully-written-by-kernel regions
    int*   bpad    = (int*)alloc(32);
    int*   blkcnt  = (int*)alloc((size_t)6 * NBC * 4);
    int*   perm    = (int*)alloc((size_t)PERMN * 4);      // filled with -1
    int*   row_ptr = (int*)alloc((size_t)(NN + 1) * 4);
    int*   cursor  = (int*)alloc((size_t)NN * 4);
    int*   col     = (int*)alloc((size_t)NE * 4);
    int*   part    = (int*)alloc(1024 * 4);
    float* pl      = (float*)alloc((size_t)NG * 2 * 4);
    _Float16* whi  = (_Float16*)alloc(WTOT * 2);          // packed weights hi
    _Float16* wlo  = (_Float16*)alloc(WTOT * 2);          // packed weights lo
    float* bufA    = (float*)alloc((size_t)NN * 128 * 4); // h0 -> m2 -> h2[:,0:128)
    float* bufB    = (float*)alloc((size_t)NN * 128 * 4); // h1 -> h2[:,128:256)

    size_t required = (size_t)(w - (char*)d_ws);
    if (required > ws_size) {
        k_report<<<(out_size + 255) / 256, 256, 0, stream>>>(
            outp, (float)(double)(ws_size >> 20), out_size);
        return;
    }

    dim3 b256(256);
    dim3 b512(512);
    k_memset32<<<(int)((zero_words + 255) / 256), b256, 0, stream>>>((int*)deg, 0, (int)zero_words);
    k_memset32<<<(PERMN + 255) / 256, b256, 0, stream>>>(perm, -1, PERMN);

    // pack all weights into fragment-ordered f16 hi/lo
    k_wpack<64, 128><<<(int)(P_L0 / 8 + 255) / 256, b256, 0, stream>>>(Wl0, Wr0, whi + O_P0, wlo + O_P0);
    k_wpack<128, 128><<<(int)(P_L1 / 8 + 255) / 256, b256, 0, stream>>>(Wl1, Wr1, whi + O_P1, wlo + O_P1);
    k_wpack<128, 256><<<(int)(P_L2 / 8 + 255) / 256, b256, 0, stream>>>(Wl2, Wr2, whi + O_P2, wlo + O_P2);
    k_wpack<256, 256><<<(int)(P_L3 / 8 + 255) / 256, b256, 0, stream>>>(Wl3, Wr3, whi + O_P3, wlo + O_P3);

    k_count_deg<<<NE / 256, b256, 0, stream>>>(dst, deg);
    k_scan_part<<<NBC, b256, 0, stream>>>(deg, part);
    k_scan_single<<<1, 1024, 0, stream>>>(part, NBC);
    k_scan_final<<<NBC, b256, 0, stream>>>(deg, part, row_ptr, cursor);
    k_fill_csr<<<NE / 256, b256, 0, stream>>>(src, dst, cursor, col);
    k_bucket_blockcount<<<NBC, b256, 0, stream>>>(deg, blkcnt);
    k_bucket_scanall<<<1, 64, 0, stream>>>(blkcnt, bpad);
    k_scatter2<<<NBC, b256, 0, stream>>>(deg, blkcnt, bpad, perm);

    // Layer 0: in=x(64) -> h0=bufA(128)
    k_transform<64, 0, 128, 4, false><<<dim3(NBLK), b512, 0, stream>>>(
        x, nullptr, row_ptr, col, whi + O_P0, wlo + O_P0,
        bl0, Wf, perm, deg, nullptr, bufA, nullptr, logits, 0);
    // Layer 1: in=bufA(128) -> h1=bufB(128)
    k_transform<128, 0, 128, 4, false><<<dim3(NBLK), b512, 0, stream>>>(
        bufA, nullptr, row_ptr, col, whi + O_P1, wlo + O_P1,
        bl1, Wf, perm, deg, nullptr, bufB, nullptr, logits, 128);
    // Layer 2a: m2 = gather-sum(h1) -> bufA
    k_aggregate128<<<NN / 4, b256, 0, stream>>>(bufB, row_ptr, col, bufA);
    // Layer 2b: h2 = [m2|h1] @ [Wl2;Wr2] + bl2, in place -> [bufA|bufB]
    k_gemm2b<<<dim3(NBLK), b512, 0, stream>>>(
        bufA, bufB, whi + O_P2, wlo + O_P2, bl2, Wf, perm, deg, logits);
    // Layer 3: in=[bufA|bufB](256) -> logits chunk + pool (h3 never stored)
    k_transform<128, 128, 256, 4, true><<<dim3(NBLK), b512, 0, stream>>>(
        bufA, bufB, row_ptr, col, whi + O_P3, wlo + O_P3,
        bl3, Wf, perm, deg, batch, nullptr, pool, logits, 512);

    k_pool_logits<<<NG / 4, b256, 0, stream>>>(pool, Wf, bf, pl);
    k_final<<<NBC, b256, 0, stream>>>(logits, pl, batch, outp);
}

// Round 10
// 1206.581 us; speedup vs baseline: 1.2388x; 1.0065x over previous
//
#include <hip/hip_runtime.h>
#include <cstdint>
#include <cstddef>

namespace {

constexpr int NN   = 200000;   // nodes
constexpr int NE   = 800000;   // edges
constexpr int NG   = 4096;     // graphs
constexpr int MAXD = 5;

constexpr int BM = 64;
constexpr int NBC = (NN + 255) / 256;           // 782 preprocessing blocks
constexpr int NBLK  = (NN + BM - 1) / BM + 6;   // 3131 (bucket padding)
constexpr int PERMN = NBLK * BM;                // 200384

typedef _Float16 half8 __attribute__((ext_vector_type(8)));
typedef _Float16 half4 __attribute__((ext_vector_type(4)));
typedef _Float16 half2 __attribute__((ext_vector_type(2)));
typedef float    f32x4 __attribute__((ext_vector_type(4)));

// packed-weight offsets (fragment-ordered, per layer: 6 * 2*CIN * COUT elems)
constexpr size_t P_L0 = (size_t)6 * 128 * 128;   // 98304
constexpr size_t P_L1 = (size_t)6 * 256 * 128;   // 196608
constexpr size_t P_L2 = (size_t)6 * 256 * 256;   // 393216
constexpr size_t P_L3 = (size_t)6 * 512 * 256;   // 786432
constexpr size_t O_P0 = 0;
constexpr size_t O_P1 = O_P0 + P_L0;
constexpr size_t O_P2 = O_P1 + P_L1;
constexpr size_t O_P3 = O_P2 + P_L2;
constexpr size_t WTOT = O_P3 + P_L3;             // 1,474,560 elements

// ---------------- init / diagnostic ----------------

__global__ void k_memset32(int* __restrict__ p, int v, int n) {
    int i = blockIdx.x * 256 + threadIdx.x;
    if (i < n) p[i] = v;
}

__global__ void k_report(float* __restrict__ outp, float v, int n) {
    int i = blockIdx.x * 256 + threadIdx.x;
    if (i < n) outp[i] = v;
}

// pack fp32 weights into MFMA B-fragment order, f16 hi/lo split.
template <int CIN, int COUT>
__global__ void k_wpack(const float* __restrict__ Wl, const float* __restrict__ Wr,
                        _Float16* __restrict__ hi, _Float16* __restrict__ lo) {
    constexpr int NT = CIN / 16;   // tiles over k = 2*CIN
    constexpr int NB = COUT / 16;
    const int total = 6 * NT * NB * 64;
    int idx = blockIdx.x * 256 + threadIdx.x;
    if (idx >= total) return;
    const int lane = idx & 63;
    int rest = idx >> 6;
    const int nb = rest % NB; rest /= NB;
    const int ti = rest % NT;
    const int d  = rest / NT;
    const int k0 = ti * 32 + ((lane >> 4) * 8);
    const int n  = nb * 16 + (lane & 15);
    half8 hv, lv;
#pragma unroll
    for (int j = 0; j < 8; j++) {
        const int kk = k0 + j;
        const float v = (kk < CIN)
                            ? Wl[((size_t)d * CIN + kk) * COUT + n]
                            : Wr[((size_t)d * CIN + (kk - CIN)) * COUT + n];
        const _Float16 h = (_Float16)v;
        hv[j] = h;
        lv[j] = (_Float16)(v - (float)h);
    }
    *(half8*)(hi + (size_t)idx * 8) = hv;
    *(half8*)(lo + (size_t)idx * 8) = lv;
}

// ---------------- graph preprocessing ----------------

__global__ void k_count_deg(const int* __restrict__ dst, int* __restrict__ deg) {
    int e = blockIdx.x * 256 + threadIdx.x;
    if (e < NE) atomicAdd(&deg[dst[e]], 1);
}

__global__ void k_scan_part(const int* __restrict__ deg, int* __restrict__ part) {
    __shared__ int s[256];
    int t = threadIdx.x, i = blockIdx.x * 256 + t;
    s[t] = (i < NN) ? deg[i] : 0;
    __syncthreads();
    for (int st = 128; st > 0; st >>= 1) {
        if (t < st) s[t] += s[t + st];
        __syncthreads();
    }
    if (t == 0) part[blockIdx.x] = s[0];
}

__global__ void k_scan_single(int* __restrict__ part, int nb) {
    __shared__ int s[1024];
    int t = threadIdx.x;
    int v0 = (t < nb) ? part[t] : 0;
    s[t] = v0;
    __syncthreads();
    for (int off = 1; off < 1024; off <<= 1) {
        int v = (t >= off) ? s[t - off] : 0;
        __syncthreads();
        s[t] += v;
        __syncthreads();
    }
    if (t < nb) part[t] = s[t] - v0;
}

__global__ void k_scan_final(const int* __restrict__ deg, const int* __restrict__ part,
                             int* __restrict__ row_ptr, int* __restrict__ cursor) {
    __shared__ int s[256];
    int t = threadIdx.x, i = blockIdx.x * 256 + t;
    int v0 = (i < NN) ? deg[i] : 0;
    s[t] = v0;
    __syncthreads();
    for (int off = 1; off < 256; off <<= 1) {
        int v = (t >= off) ? s[t - off] : 0;
        __syncthreads();
        s[t] += v;
        __syncthreads();
    }
    if (i < NN) {
        int excl = s[t] - v0 + part[blockIdx.x];
        row_ptr[i] = excl;
        cursor[i]  = excl;
        if (i == NN - 1) row_ptr[NN] = excl + v0;
    }
}

__global__ void k_fill_csr(const int* __restrict__ src, const int* __restrict__ dst,
                           int* __restrict__ cursor, int* __restrict__ col) {
    int e = blockIdx.x * 256 + threadIdx.x;
    if (e < NE) {
        int d = dst[e];
        int slot = atomicAdd(&cursor[d], 1);
        col[slot] = src[e];
    }
}

// -- two-level COARSE bucket counting sort (keeps perm ~node-ordered within
// -- each min(deg,5) bucket; fine sort destroyed locality - round-17) --

__global__ void k_bucket_blockcount(const int* __restrict__ deg, int* __restrict__ blkcnt) {
    __shared__ int h[6];
    int t = threadIdx.x;
    if (t < 6) h[t] = 0;
    __syncthreads();
    int i = blockIdx.x * 256 + t;
    if (i < NN) atomicAdd(&h[min(deg[i], MAXD)], 1);
    __syncthreads();
    if (t < 6) blkcnt[t * NBC + blockIdx.x] = h[t];
}

__global__ void k_bucket_scanall(int* __restrict__ blkcnt, int* __restrict__ bpad) {
    __shared__ int tot[6];
    int t = threadIdx.x;
    if (t < 6) {
        int run = 0;
        for (int j = 0; j < NBC; j++) {
            int v = blkcnt[t * NBC + j];
            blkcnt[t * NBC + j] = run;
            run += v;
        }
        tot[t] = run;
    }
    __syncthreads();
    if (t == 0) {
        int off = 0;
        for (int b = 0; b < 6; b++) {
            bpad[b] = off;
            off += ((tot[b] + BM - 1) / BM) * BM;
        }
        bpad[6] = off;
    }
}

__global__ void k_scatter2(const int* __restrict__ deg, const int* __restrict__ blkcnt,
                           const int* __restrict__ bpad, int* __restrict__ perm) {
    __shared__ int base[6];
    int t = threadIdx.x;
    if (t < 6) base[t] = bpad[t] + blkcnt[t * NBC + blockIdx.x];
    __syncthreads();
    int i = blockIdx.x * 256 + t;
    if (i < NN) {
        int b = min(deg[i], MAXD);
        int pos = atomicAdd(&base[b], 1);
        perm[pos] = i;
    }
}

// ---------------- layer-2a: plain neighbor-sum aggregate ----------------

__global__ void k_aggregate128(const float* __restrict__ hin, const int* __restrict__ row_ptr,
                               const int* __restrict__ col, float* __restrict__ msg) {
    int node = blockIdx.x * 4 + (threadIdx.x >> 6);
    int lane = threadIdx.x & 63;
    int s = row_ptr[node], e = row_ptr[node + 1];
    float2 acc = make_float2(0.f, 0.f);
    int p = s;
    for (; p + 4 <= e; p += 4) {
        const int c0 = col[p], c1 = col[p + 1], c2 = col[p + 2], c3 = col[p + 3];
        const float2 v0 = *(const float2*)(hin + (size_t)c0 * 128 + lane * 2);
        const float2 v1 = *(const float2*)(hin + (size_t)c1 * 128 + lane * 2);
        const float2 v2 = *(const float2*)(hin + (size_t)c2 * 128 + lane * 2);
        const float2 v3 = *(const float2*)(hin + (size_t)c3 * 128 + lane * 2);
        acc.x += (v0.x + v1.x) + (v2.x + v3.x);
        acc.y += (v0.y + v1.y) + (v2.y + v3.y);
    }
    for (; p < e; p++) {
        const float2 v = *(const float2*)(hin + (size_t)col[p] * 128 + lane * 2);
        acc.x += v.x; acc.y += v.y;
    }
    *(float2*)(msg + (size_t)node * 128 + lane * 2) = acc;
}

// ---------------- fused aggregate + transform (round-20) -------------------
//
// Round-19 cycle accounting: layer-3 = ~175K cycles/BLOCK vs ~12K of modeled
// work.  The only resource at that scale is VMEM TRANSACTION throughput:
// scattered gather = 64 lanes x 64 DIFFERENT rows per instruction = 64
// cache-line transactions @ ~1/cyc/CU.  51M transactions / 256 CU = 200K
// cyc/CU = the measured floor.  Round-13's coalesced gather was the right
// fix but was tested while 54M pool atomics (also transactions) dominated -
// never retried after the round-14 atomic fix.
// Round-20 = round-16 epilogue/phases + WAVE-PER-ROW COALESCED memory shape
// everywhere: gather, root staging, gemm2b staging (one instruction covers
// a contiguous row slice -> ~12 transactions/edge instead of 64).
template <int C0, int C1, int COUT, int MINW, bool POOL_FUSE>
__launch_bounds__(512, MINW)
__global__ void k_transform(const float* __restrict__ hin0, const float* __restrict__ hin1,
                            const int* __restrict__ row_ptr, const int* __restrict__ col,
                            const _Float16* __restrict__ wph, const _Float16* __restrict__ wpl,
                            const float* __restrict__ bias, const float* __restrict__ Wf,
                            const int* __restrict__ perm, const int* __restrict__ deg,
                            const int* __restrict__ batch,
                            float* __restrict__ out0, float* __restrict__ pool,
                            float* __restrict__ logits, int wf_off) {
    constexpr int CIN = C0 + C1;
    constexpr int NW  = CIN / 32;        // k-tiles per operand half (msg/root)
    constexpr int NT  = 2 * NW;          // total k-tiles (weight indexing)
    constexpr int NB  = COUT / 16;
    constexpr int NTN = NB / 8;          // n-tiles per wave (8 waves)
    constexpr int CPL = CIN / 64;        // floats per LANE (coalesced slice)
    constexpr int PB_R = POOL_FUSE ? 64 : 1;   // pool staging rows
    constexpr int PB_C = 258;                  // stride == 2 mod 8: 2-way free

    struct FragBuf {
        _Float16 Ah[NW][4][64][8];
        _Float16 Al[NW][4][64][8];
    };
    union SMemU {
        FragBuf f;
        float pbuf[PB_R][PB_C];
    };
    __shared__ SMemU sm;
    __shared__ int rowid[BM];
    __shared__ int gb[BM];
    __shared__ float lsx[8][BM], lsy[8][BM];   // per-wave logits partials

    const int t  = threadIdx.x;
    const int m0 = blockIdx.x * BM;

    if (t < BM) rowid[t] = perm[m0 + t];
    __syncthreads();
    if (rowid[0] < 0) return;  // fully-padded block (uniform exit)

    const int d = min(deg[rowid[0]], MAXD);

    const int am = t & 63, wv = t >> 6;   // lane, wave (0..7)

    if constexpr (POOL_FUSE) {
        if (t < BM) gb[t] = (rowid[t] >= 0) ? batch[rowid[t]] : -1;
    }

    // lane's k-slice (coalesced): kk = CPL*am, never straddles C0|C1
    const int kk = CPL * am;
    const bool lo_half = (C1 == 0) || (kk < C0);
    const float* gsrc = lo_half ? hin0 : hin1;
    const int    gst  = lo_half ? C0 : C1;
    const int    goff = lo_half ? kk : (kk - C0);
    const int ti0 = kk >> 5;
    const int o0  = (kk >> 3) & 3;
    const int j00 = kk & 7;

    // ---- phase 1: wave-per-row COALESCED gather + fragment staging ----
    {
#pragma unroll
        for (int i = 0; i < 8; i++) {
            const int r = wv * 8 + i;
            const int node = rowid[r];
            float a0 = 0.f, a1 = 0.f, a2 = 0.f, a3 = 0.f;
            if (node >= 0) {
                const int es = row_ptr[node], ee = row_ptr[node + 1];
                int p = es;
                for (; p + 4 <= ee; p += 4) {
                    const int c0 = col[p], c1 = col[p + 1];
                    const int c2 = col[p + 2], c3 = col[p + 3];
                    const float* r0 = gsrc + (size_t)c0 * gst + goff;
                    const float* r1 = gsrc + (size_t)c1 * gst + goff;
                    const float* r2 = gsrc + (size_t)c2 * gst + goff;
                    const float* r3 = gsrc + (size_t)c3 * gst + goff;
                    if constexpr (CPL == 4) {
                        f32x4 v0 = *(const f32x4*)r0, v1 = *(const f32x4*)r1;
                        f32x4 v2 = *(const f32x4*)r2, v3 = *(const f32x4*)r3;
                        v0 += v1; v2 += v3; v0 += v2;
                        a0 += v0[0]; a1 += v0[1]; a2 += v0[2]; a3 += v0[3];
                    } else if constexpr (CPL == 2) {
                        float2 v0 = *(const float2*)r0, v1 = *(const float2*)r1;
                        float2 v2 = *(const float2*)r2, v3 = *(const float2*)r3;
                        a0 += (v0.x + v1.x) + (v2.x + v3.x);
                        a1 += (v0.y + v1.y) + (v2.y + v3.y);
                    } else {
                        a0 += (*r0 + *r1) + (*r2 + *r3);
                    }
                }
                for (; p < ee; p++) {
                    const float* rr = gsrc + (size_t)col[p] * gst + goff;
                    if constexpr (CPL == 4) {
                        f32x4 v = *(const f32x4*)rr;
                        a0 += v[0]; a1 += v[1]; a2 += v[2]; a3 += v[3];
                    } else if constexpr (CPL == 2) {
                        float2 v = *(const float2*)rr;
                        a0 += v.x; a1 += v.y;
                    } else {
                        a0 += *rr;
                    }
                }
            }
            const int mt = r >> 4, rl = r & 15;
            if constexpr (CPL == 4) {
                half4 hv, lv;
                hv[0] = (_Float16)a0; lv[0] = (_Float16)(a0 - (float)hv[0]);
                hv[1] = (_Float16)a1; lv[1] = (_Float16)(a1 - (float)hv[1]);
                hv[2] = (_Float16)a2; lv[2] = (_Float16)(a2 - (float)hv[2]);
                hv[3] = (_Float16)a3; lv[3] = (_Float16)(a3 - (float)hv[3]);
                *(half4*)&sm.f.Ah[ti0][mt][rl + 16 * o0][j00] = hv;
                *(half4*)&sm.f.Al[ti0][mt][rl + 16 * o0][j00] = lv;
            } else if constexpr (CPL == 2) {
                half2 hv, lv;
                hv[0] = (_Float16)a0; lv[0] = (_Float16)(a0 - (float)hv[0]);
                hv[1] = (_Float16)a1; lv[1] = (_Float16)(a1 - (float)hv[1]);
                *(half2*)&sm.f.Ah[ti0][mt][rl + 16 * o0][j00] = hv;
                *(half2*)&sm.f.Al[ti0][mt][rl + 16 * o0][j00] = lv;
            } else {
                const _Float16 h = (_Float16)a0;
                sm.f.Ah[ti0][mt][rl + 16 * o0][j00] = h;
                sm.f.Al[ti0][mt][rl + 16 * o0][j00] = (_Float16)(a0 - (float)h);
            }
        }
    }
    __syncthreads();

    const int lx = t & 15, qd = (t >> 4) & 3;
    const int nb0 = wv * NTN;

    f32x4 acc[4][NTN];
#pragma unroll
    for (int mt = 0; mt < 4; mt++)
#pragma unroll
        for (int nt = 0; nt < NTN; nt++) acc[mt][nt] = (f32x4)0.f;

    // ---- phase 2a: msg-tile MFMA sweep (A from LDS) ----
    for (int ti = 0; ti < NW; ti++) {
        half8 bh[NTN], bl[NTN];
        const size_t tbase = (((size_t)d * NT + ti) * NB) * 512;
#pragma unroll
        for (int nt = 0; nt < NTN; nt++) {
            const size_t off = tbase + (size_t)(nb0 + nt) * 512 + (size_t)am * 8;
            bh[nt] = *(const half8*)(wph + off);
            bl[nt] = *(const half8*)(wpl + off);
        }
        half8 ah[4], alo[4];
#pragma unroll
        for (int mt = 0; mt < 4; mt++) {
            ah[mt]  = *(const half8*)&sm.f.Ah[ti][mt][am][0];
            alo[mt] = *(const half8*)&sm.f.Al[ti][mt][am][0];
        }
#pragma unroll
        for (int nt = 0; nt < NTN; nt++)
#pragma unroll
            for (int mt = 0; mt < 4; mt++) {
                acc[mt][nt] = __builtin_amdgcn_mfma_f32_16x16x32_f16(ah[mt],  bh[nt], acc[mt][nt], 0, 0, 0);
                acc[mt][nt] = __builtin_amdgcn_mfma_f32_16x16x32_f16(alo[mt], bh[nt], acc[mt][nt], 0, 0, 0);
                acc[mt][nt] = __builtin_amdgcn_mfma_f32_16x16x32_f16(ah[mt],  bl[nt], acc[mt][nt], 0, 0, 0);
            }
    }
    __syncthreads();   // all msg-fragment reads done before buffer reuse

    // ---- phase 1b: coalesced root staging (one row-slice load per lane) ----
    {
#pragma unroll
        for (int i = 0; i < 8; i++) {
            const int r = wv * 8 + i;
            const int node = rowid[r];
            const int mt = r >> 4, rl = r & 15;
            if constexpr (CPL == 4) {
                f32x4 v = (f32x4)0.f;
                if (node >= 0) v = *(const f32x4*)(gsrc + (size_t)node * gst + goff);
                half4 hv, lv;
#pragma unroll
                for (int c = 0; c < 4; c++) {
                    const _Float16 h = (_Float16)v[c];
                    hv[c] = h; lv[c] = (_Float16)(v[c] - (float)h);
                }
                *(half4*)&sm.f.Ah[ti0][mt][rl + 16 * o0][j00] = hv;
                *(half4*)&sm.f.Al[ti0][mt][rl + 16 * o0][j00] = lv;
            } else if constexpr (CPL == 2) {
                float2 v = make_float2(0.f, 0.f);
                if (node >= 0) v = *(const float2*)(gsrc + (size_t)node * gst + goff);
                half2 hv, lv;
                hv[0] = (_Float16)v.x; lv[0] = (_Float16)(v.x - (float)hv[0]);
                hv[1] = (_Float16)v.y; lv[1] = (_Float16)(v.y - (float)hv[1]);
                *(half2*)&sm.f.Ah[ti0][mt][rl + 16 * o0][j00] = hv;
                *(half2*)&sm.f.Al[ti0][mt][rl + 16 * o0][j00] = lv;
            } else {
                float v = 0.f;
                if (node >= 0) v = gsrc[(size_t)node * gst + goff];
                const _Float16 h = (_Float16)v;
                sm.f.Ah[ti0][mt][rl + 16 * o0][j00] = h;
                sm.f.Al[ti0][mt][rl + 16 * o0][j00] = (_Float16)(v - (float)h);
            }
        }
    }
    __syncthreads();

    // ---- phase 2b: root-tile MFMA sweep (A from LDS) ----
    for (int ti = 0; ti < NW; ti++) {
        half8 bh[NTN], bl[NTN];
        const size_t tbase = (((size_t)d * NT + NW + ti) * NB) * 512;
#pragma unroll
        for (int nt = 0; nt < NTN; nt++) {
            const size_t off = tbase + (size_t)(nb0 + nt) * 512 + (size_t)am * 8;
            bh[nt] = *(const half8*)(wph + off);
            bl[nt] = *(const half8*)(wpl + off);
        }
        half8 ah[4], alo[4];
#pragma unroll
        for (int mt = 0; mt < 4; mt++) {
            ah[mt]  = *(const half8*)&sm.f.Ah[ti][mt][am][0];
            alo[mt] = *(const half8*)&sm.f.Al[ti][mt][am][0];
        }
#pragma unroll
        for (int nt = 0; nt < NTN; nt++)
#pragma unroll
            for (int mt = 0; mt < 4; mt++) {
                acc[mt][nt] = __builtin_amdgcn_mfma_f32_16x16x32_f16(ah[mt],  bh[nt], acc[mt][nt], 0, 0, 0);
                acc[mt][nt] = __builtin_amdgcn_mfma_f32_16x16x32_f16(alo[mt], bh[nt], acc[mt][nt], 0, 0, 0);
                acc[mt][nt] = __builtin_amdgcn_mfma_f32_16x16x32_f16(ah[mt],  bl[nt], acc[mt][nt], 0, 0, 0);
            }
    }

    // epilogue: lane cols are wv*16*NTN + nt*16 + lx
    float blv[NTN], w0[NTN], w1[NTN];
    int cols[NTN];
#pragma unroll
    for (int nt = 0; nt < NTN; nt++) {
        cols[nt] = wv * (16 * NTN) + nt * 16 + lx;
        blv[nt] = bias[d * COUT + cols[nt]];
        w0[nt]  = Wf[(size_t)(wf_off + cols[nt]) * 2 + 0];
        w1[nt]  = Wf[(size_t)(wf_off + cols[nt]) * 2 + 1];
    }

    // all waves must finish root-fragment reads before pbuf aliasing reuse
    __syncthreads();

#pragma unroll
    for (int mt = 0; mt < 4; mt++)
#pragma unroll
    for (int r = 0; r < 4; r++) {
        const int ri = mt * 16 + qd * 4 + r;
        const int node = rowid[ri];
        float p0 = 0.f, p1 = 0.f;
        float h[NTN];
#pragma unroll
        for (int nt = 0; nt < NTN; nt++) h[nt] = 0.f;
        if (node >= 0) {
#pragma unroll
            for (int nt = 0; nt < NTN; nt++) {
                h[nt] = acc[mt][nt][r] + blv[nt];
                p0 = fmaf(h[nt], w0[nt], p0);
                p1 = fmaf(h[nt], w1[nt], p1);
            }
            if constexpr (!POOL_FUSE) {
                float* orow = out0 + (size_t)node * COUT;
#pragma unroll
                for (int nt = 0; nt < NTN; nt++) orow[cols[nt]] = h[nt];
            }
        }
        if constexpr (POOL_FUSE) {
#pragma unroll
            for (int nt = 0; nt < NTN; nt++) sm.pbuf[ri][cols[nt]] = h[nt];
        }
#pragma unroll
        for (int s = 1; s < 16; s <<= 1) {
            p0 += __shfl_xor(p0, s, 64);
            p1 += __shfl_xor(p1, s, 64);
        }
        if (lx == 0) {          // plain per-wave store (each ri once per wave)
            lsx[wv][ri] = p0;
            lsy[wv][ri] = p1;
        }
    }
    __syncthreads();

    // logits flush: reduce 8 per-wave partials, plain RMW (block owns rows)
    if (t < BM) {
        const int node = rowid[t];
        if (node >= 0) {
            float sx = 0.f, sy = 0.f;
#pragma unroll
            for (int w = 0; w < 8; w++) { sx += lsx[w][t]; sy += lsy[w][t]; }
            logits[(size_t)node * 2 + 0] += sx;
            logits[(size_t)node * 2 + 1] += sy;
        }
    }

    // pool flush: run-compressed by graph id -> ~1 atomic per (run,col)
    if constexpr (POOL_FUSE) {
        const int c  = t & 255;     // col
        const int rh = t >> 8;      // row-half 0/1
        float run = 0.f;
        int rg = -1;
        const int r0 = rh * 32, r1 = r0 + 32;
        for (int r = r0; r < r1; r++) {
            const int g = gb[r];
            if (g != rg) {
                if (rg >= 0) atomicAdd(&pool[(size_t)rg * 256 + c], run);
                run = 0.f; rg = g;
            }
            if (g >= 0) run += sm.pbuf[r][c];
        }
        if (rg >= 0) atomicAdd(&pool[(size_t)rg * 256 + c], run);
    }
}

// ---------------- layer-2b: full-width MFMA GEMM, in-place (coalesced) -----

__launch_bounds__(512, 4)
__global__ void k_gemm2b(float* __restrict__ buf0, float* __restrict__ buf1,
                         const _Float16* __restrict__ wph, const _Float16* __restrict__ wpl,
                         const float* __restrict__ bias, const float* __restrict__ Wf,
                         const int* __restrict__ perm, const int* __restrict__ deg,
                         float* __restrict__ logits) {
    constexpr int COUT = 256, NT = 8, NB = 16, NTN = 2;
    __shared__ _Float16 Ah[NT][4][64][8];   // 32 KB
    __shared__ _Float16 Al[NT][4][64][8];   // 32 KB
    __shared__ int rowid[BM];
    __shared__ float lsx[8][BM], lsy[8][BM];

    const int t  = threadIdx.x;
    const int m0 = blockIdx.x * BM;

    if (t < BM) rowid[t] = perm[m0 + t];
    __syncthreads();
    if (rowid[0] < 0) return;

    const int d = min(deg[rowid[0]], MAXD);

    const int am = t & 63, wv = t >> 6;

    // phase 1: wave-per-row coalesced staging (node wave-uniform -> 1KB burst)
    {
        const int kk = 4 * am;                        // lane's k-slice [kk,kk+4)
        const float* gsrc = (am < 32) ? buf0 : buf1;
        const int    goff = (am < 32) ? kk : (kk - 128);
        const int ti = am >> 3;
        const int o  = (am >> 1) & 3;
        const int j0 = 4 * (am & 1);
#pragma unroll
        for (int i = 0; i < 8; i++) {
            const int r = wv * 8 + i;
            const int node = rowid[r];
            f32x4 v = (f32x4)0.f;
            if (node >= 0) v = *(const f32x4*)(gsrc + (size_t)node * 128 + goff);
            const int mt = r >> 4, rl = r & 15;
            half4 hv, lv;
#pragma unroll
            for (int c = 0; c < 4; c++) {
                const _Float16 h = (_Float16)v[c];
                hv[c] = h; lv[c] = (_Float16)(v[c] - (float)h);
            }
            *(half4*)&Ah[ti][mt][rl + 16 * o][j0] = hv;
            *(half4*)&Al[ti][mt][rl + 16 * o][j0] = lv;
        }
    }
    __syncthreads();

    const int lx = t & 15, qd = (t >> 4) & 3;
    const int nb0 = wv * NTN;

    f32x4 acc[4][NTN];
#pragma unroll
    for (int mt = 0; mt < 4; mt++)
#pragma unroll
        for (int nt = 0; nt < NTN; nt++) acc[mt][nt] = (f32x4)0.f;

    for (int ti = 0; ti < NT; ti++) {
        half8 bh[NTN], bl[NTN];
        const size_t tbase = (((size_t)d * NT + ti) * NB) * 512;
#pragma unroll
        for (int nt = 0; nt < NTN; nt++) {
            const size_t off = tbase + (size_t)(nb0 + nt) * 512 + (size_t)am * 8;
            bh[nt] = *(const half8*)(wph + off);
            bl[nt] = *(const half8*)(wpl + off);
        }
        half8 ah[4], alo[4];
#pragma unroll
        for (int mt = 0; mt < 4; mt++) {
            ah[mt]  = *(const half8*)&Ah[ti][mt][am][0];
            alo[mt] = *(const half8*)&Al[ti][mt][am][0];
        }
#pragma unroll
        for (int nt = 0; nt < NTN; nt++)
#pragma unroll
            for (int mt = 0; mt < 4; mt++) {
                acc[mt][nt] = __builtin_amdgcn_mfma_f32_16x16x32_f16(ah[mt],  bh[nt], acc[mt][nt], 0, 0, 0);
                acc[mt][nt] = __builtin_amdgcn_mfma_f32_16x16x32_f16(alo[mt], bh[nt], acc[mt][nt], 0, 0, 0);
                acc[mt][nt] = __builtin_amdgcn_mfma_f32_16x16x32_f16(ah[mt],  bl[nt], acc[mt][nt], 0, 0, 0);
            }
    }

    // epilogue: in-place split write + per-wave logits partials (no atomics)
    float blv[NTN], w0[NTN], w1[NTN];
    int cols[NTN];
#pragma unroll
    for (int nt = 0; nt < NTN; nt++) {
        cols[nt] = wv * 32 + nt * 16 + lx;
        blv[nt] = bias[d * COUT + cols[nt]];
        w0[nt]  = Wf[(size_t)(256 + cols[nt]) * 2 + 0];
        w1[nt]  = Wf[(size_t)(256 + cols[nt]) * 2 + 1];
    }
#pragma unroll
    for (int mt = 0; mt < 4; mt++)
#pragma unroll
    for (int r = 0; r < 4; r++) {
        const int ri = mt * 16 + qd * 4 + r;
        const int node = rowid[ri];
        float p0 = 0.f, p1 = 0.f;
        if (node >= 0) {
#pragma unroll
            for (int nt = 0; nt < NTN; nt++) {
                const float h = acc[mt][nt][r] + blv[nt];
                p0 = fmaf(h, w0[nt], p0);
                p1 = fmaf(h, w1[nt], p1);
                if (cols[nt] < 128) buf0[(size_t)node * 128 + cols[nt]] = h;
                else                buf1[(size_t)node * 128 + cols[nt] - 128] = h;
            }
        }
#pragma unroll
        for (int s = 1; s < 16; s <<= 1) {
            p0 += __shfl_xor(p0, s, 64);
            p1 += __shfl_xor(p1, s, 64);
        }
        if (lx == 0) {
            lsx[wv][ri] = p0;
            lsy[wv][ri] = p1;
        }
    }
    __syncthreads();
    if (t < BM) {
        const int node = rowid[t];
        if (node >= 0) {
            float sx = 0.f, sy = 0.f;
#pragma unroll
            for (int w = 0; w < 8; w++) { sx += lsx[w][t]; sy += lsy[w][t]; }
            logits[(size_t)node * 2 + 0] += sx;
            logits[(size_t)node * 2 + 1] += sy;
        }
    }
}

// ---------------- pooling / output ----------------

__global__ void k_pool_logits(const float* __restrict__ pool, const float* __restrict__ Wf,
                              const float* __restrict__ bf, float* __restrict__ pl) {
    int g = blockIdx.x * 4 + (threadIdx.x >> 6);
    int lane = threadIdx.x & 63;
    const float* pr = pool + (size_t)g * 256;
    float p0 = 0.f, p1 = 0.f;
#pragma unroll
    for (int j = 0; j < 4; j++) {
        int k = lane + 64 * j;
        float v = pr[k];
        p0 = fmaf(v, Wf[(size_t)(768 + k) * 2 + 0], p0);
        p1 = fmaf(v, Wf[(size_t)(768 + k) * 2 + 1], p1);
    }
#pragma unroll
    for (int s = 1; s < 64; s <<= 1) {
        p0 += __shfl_xor(p0, s, 64);
        p1 += __shfl_xor(p1, s, 64);
    }
    if (lane == 0) {
        pl[(size_t)g * 2 + 0] = p0 + bf[0];
        pl[(size_t)g * 2 + 1] = p1 + bf[1];
    }
}

__global__ void k_final(const float* __restrict__ logits, const float* __restrict__ pl,
                        const int* __restrict__ batch, float* __restrict__ outp) {
    int i = blockIdx.x * 256 + threadIdx.x;
    if (i < NN) {
        int g = batch[i];
        float l0 = logits[(size_t)i * 2 + 0] + pl[(size_t)g * 2 + 0];
        float l1 = logits[(size_t)i * 2 + 1] + pl[(size_t)g * 2 + 1];
        float m = fmaxf(l0, l1);
        float e0 = expf(l0 - m), e1 = expf(l1 - m);
        float inv = 1.f / (e0 + e1);
        outp[(size_t)i * 2 + 0] = e0 * inv;
        outp[(size_t)i * 2 + 1] = e1 * inv;
    }
}

}  // namespace

extern "C" void kernel_launch(void* const* d_in, const int* in_sizes, int n_in,
                              void* d_out, int out_size, void* d_ws, size_t ws_size,
                              hipStream_t stream) {
    const float* x     = (const float*)d_in[0];
    const int*   ei    = (const int*)d_in[1];
    const int*   batch = (const int*)d_in[2];
    const float* Wl0 = (const float*)d_in[3];  const float* bl0 = (const float*)d_in[4];
    const float* Wr0 = (const float*)d_in[5];
    const float* Wl1 = (const float*)d_in[6];  const float* bl1 = (const float*)d_in[7];
    const float* Wr1 = (const float*)d_in[8];
    const float* Wl2 = (const float*)d_in[9];  const float* bl2 = (const float*)d_in[10];
    const float* Wr2 = (const float*)d_in[11];
    const float* Wl3 = (const float*)d_in[12]; const float* bl3 = (const float*)d_in[13];
    const float* Wr3 = (const float*)d_in[14];
    const float* Wf  = (const float*)d_in[15]; const float* bf  = (const float*)d_in[16];
    const int* src = ei;
    const int* dst = ei + NE;
    float* outp = (float*)d_out;
    (void)in_sizes; (void)n_in;

    // workspace bump allocator (256B aligned).  Total ≈ 224 MB (ws is 256 MB).
    char* w = (char*)d_ws;
    auto alloc = [&](size_t bytes) -> void* {
        void* p = (void*)w;
        w += (bytes + 255) & ~(size_t)255;
        return p;
    };
    // zero-init region (contiguous): deg .. pool
    int*   deg    = (int*)alloc((size_t)NN * 4);
    float* logits = (float*)alloc((size_t)NN * 2 * 4);
    float* pool   = (float*)alloc((size_t)NG * 256 * 4);
    size_t zero_words = (size_t)(w - (char*)deg) / 4;
    // fully-written-by-kernel regions
    int*   bpad    = (int*)alloc(32);
    int*   blkcnt  = (int*)alloc((size_t)6 * NBC * 4);
    int*   perm    = (int*)alloc((size_t)PERMN * 4);      // filled with -1
    int*   row_ptr = (int*)alloc((size_t)(NN + 1) * 4);
    int*   cursor  = (int*)alloc((size_t)NN * 4);
    int*   col     = (int*)alloc((size_t)NE * 4);
    int*   part    = (int*)alloc(1024 * 4);
    float* pl      = (float*)alloc((size_t)NG * 2 * 4);
    _Float16* whi  = (_Float16*)alloc(WTOT * 2);          // packed weights hi
    _Float16* wlo  = (_Float16*)alloc(WTOT * 2);          // packed weights lo
    float* bufA    = (float*)alloc((size_t)NN * 128 * 4); // h0 -> m2 -> h2[:,0:128)
    float* bufB    = (float*)alloc((size_t)NN * 128 * 4); // h1 -> h2[:,128:256)

    size_t required = (size_t)(w - (char*)d_ws);
    if (required > ws_size) {
        k_report<<<(out_size + 255) / 256, 256, 0, stream>>>(
            outp, (float)(double)(ws_size >> 20), out_size);
        return;
    }

    dim3 b256(256);
    dim3 b512(512);
    k_memset32<<<(int)((zero_words + 255) / 256), b256, 0, stream>>>((int*)deg, 0, (int)zero_words);
    k_memset32<<<(PERMN + 255) / 256, b256, 0, stream>>>(perm, -1, PERMN);

    // pack all weights into fragment-ordered f16 hi/lo
    k_wpack<64, 128><<<(int)(P_L0 / 8 + 255) / 256, b256, 0, stream>>>(Wl0, Wr0, whi + O_P0, wlo + O_P0);
    k_wpack<128, 128><<<(int)(P_L1 / 8 + 255) / 256, b256, 0, stream>>>(Wl1, Wr1, whi + O_P1, wlo + O_P1);
    k_wpack<128, 256><<<(int)(P_L2 / 8 + 255) / 256, b256, 0, stream>>>(Wl2, Wr2, whi + O_P2, wlo + O_P2);
    k_wpack<256, 256><<<(int)(P_L3 / 8 + 255) / 256, b256, 0, stream>>>(Wl3, Wr3, whi + O_P3, wlo + O_P3);

    k_count_deg<<<NE / 256, b256, 0, stream>>>(dst, deg);
    k_scan_part<<<NBC, b256, 0, stream>>>(deg, part);
    k_scan_single<<<1, 1024, 0, stream>>>(part, NBC);
    k_scan_final<<<NBC, b256, 0, stream>>>(deg, part, row_ptr, cursor);
    k_fill_csr<<<NE / 256, b256, 0, stream>>>(src, dst, cursor, col);
    k_bucket_blockcount<<<NBC, b256, 0, stream>>>(deg, blkcnt);
    k_bucket_scanall<<<1, 64, 0, stream>>>(blkcnt, bpad);
    k_scatter2<<<NBC, b256, 0, stream>>>(deg, blkcnt, bpad, perm);

    // Layer 0: in=x(64) -> h0=bufA(128)
    k_transform<64, 0, 128, 4, false><<<dim3(NBLK), b512, 0, stream>>>(
        x, nullptr, row_ptr, col, whi + O_P0, wlo + O_P0,
        bl0, Wf, perm, deg, nullptr, bufA, nullptr, logits, 0);
    // Layer 1: in=bufA(128) -> h1=bufB(128)
    k_transform<128, 0, 128, 4, false><<<dim3(NBLK), b512, 0, stream>>>(
        bufA, nullptr, row_ptr, col, whi + O_P1, wlo + O_P1,
        bl1, Wf, perm, deg, nullptr, bufB, nullptr, logits, 128);
    // Layer 2a: m2 = gather-sum(h1) -> bufA
    k_aggregate128<<<NN / 4, b256, 0, stream>>>(bufB, row_ptr, col, bufA);
    // Layer 2b: h2 = [m2|h1] @ [Wl2;Wr2] + bl2, in place -> [bufA|bufB]
    k_gemm2b<<<dim3(NBLK), b512, 0, stream>>>(
        bufA, bufB, whi + O_P2, wlo + O_P2, bl2, Wf, perm, deg, logits);
    // Layer 3: in=[bufA|bufB](256) -> logits chunk + pool (h3 never stored)
    k_transform<128, 128, 256, 4, true><<<dim3(NBLK), b512, 0, stream>>>(
        bufA, bufB, row_ptr, col, whi + O_P3, wlo + O_P3,
        bl3, Wf, perm, deg, batch, nullptr, pool, logits, 512);

    k_pool_logits<<<NG / 4, b256, 0, stream>>>(pool, Wf, bf, pl);
    k_final<<<NBC, b256, 0, stream>>>(logits, pl, batch, outp);
}